// Round 16
// baseline (777.945 us; speedup 1.0000x reference)
//
#include <hip/hip_runtime.h>

#define DIV_UP(a,b) (((a)+(b)-1)/(b))

typedef unsigned short u16;
typedef __attribute__((ext_vector_type(8))) short s8v;
typedef __attribute__((ext_vector_type(4))) float f4v;
typedef __attribute__((ext_vector_type(2))) unsigned int u2v;

__device__ __forceinline__ float b2f(u16 x) {
    return __uint_as_float(((unsigned)x) << 16);
}
__device__ __forceinline__ u16 f2b(float f) {
    unsigned u = __float_as_uint(f);
    return (u16)((u + 0x7FFFu + ((u >> 16) & 1u)) >> 16);
}

#define GLD16(gp, lp) __builtin_amdgcn_global_load_lds( \
    (const __attribute__((address_space(1))) unsigned int*)(gp), \
    (__attribute__((address_space(3))) unsigned int*)(lp), 16, 0, 0)

// ===========================================================================
// combined halo zero: 6 halo'd NHWC buffers (runs AFTER warp stage)
// ===========================================================================
struct HZ { u16* p; int H, W, C; };
struct HZ6 { HZ d[6]; };
__global__ __launch_bounds__(256) void halo_zero(HZ6 Z)
{
    HZ d = Z.d[blockIdx.y];
    int pw = d.W + 2, ph = d.H + 2;
    int tot = 4 * ph * pw;
    int idx = blockIdx.x * 256 + threadIdx.x;
    if (idx >= tot) return;
    int r = idx % (ph * pw);
    int y = r / pw, x = r - y * pw;
    if (y > 0 && y <= d.H && x > 0 && x <= d.W) return;
    u16* p = d.p + (size_t)idx * d.C;
    s8v z = {0,0,0,0,0,0,0,0};
    for (int c = 0; c < d.C; c += 8) *(s8v*)(p + c) = z;
}

// ===========================================================================
// weight transpose: W[Cout][Cin][3][3] f32 -> W'[9][COUTP][CINP] bf16
// ===========================================================================
struct WT { const float* src; u16* dst; int Cout, Cin, COUTP, CINP, shift; };
struct WT10 { WT d[10]; };
__global__ __launch_bounds__(256) void wtrans(WT10 Z)
{
    WT d = Z.d[blockIdx.y];
    int tot = 9 * d.COUTP * d.CINP;
    int idx = blockIdx.x * 256 + threadIdx.x;
    if (idx >= tot) return;
    int s = idx / (d.COUTP * d.CINP);
    int r = idx - s * (d.COUTP * d.CINP);
    int co = r / d.CINP, ci = r - co * d.CINP;
    int sci = ci;
    bool ok = (co < d.Cout);
    if (d.shift) {
        if (ci < 6)                 sci = ci;
        else if (ci >= 8 && ci < 72) sci = ci - 2;
        else                        ok = false;
    }
    ok = ok && (sci < d.Cin);
    float v = ok ? d.src[((size_t)co * d.Cin + sci) * 9 + s] : 0.f;
    d.dst[idx] = f2b(v);
}

// ===========================================================================
// composed up2x+conv weights for u2 (parity decomposition):
// K[p][sy*3+sx][co][ci] = sum_{dy,dx} wu2[co][ci][dy][dx]*M[py][dy][sy]*M[px][dx][sx]
// layout [4][9][80][64] bf16, co>=70 zero-padded.
// ===========================================================================
__global__ __launch_bounds__(256) void wtrans2(
    const float* __restrict__ w, u16* __restrict__ dst)
{
    const float M[2][3][3] = {
        {{0.75f,0.25f,0.f},{0.25f,0.75f,0.f},{0.f,0.75f,0.25f}},
        {{0.25f,0.75f,0.f},{0.f,0.75f,0.25f},{0.f,0.25f,0.75f}} };
    int idx = blockIdx.x * 256 + threadIdx.x;
    if (idx >= 4 * 9 * 80 * 64) return;
    int p = idx / (9 * 80 * 64);
    int r = idx - p * (9 * 80 * 64);
    int s = r / (80 * 64);
    int rr = r - s * (80 * 64);
    int co = rr / 64, ci = rr - co * 64;
    int sy = s / 3, sx = s - sy * 3;
    int py = p >> 1, px = p & 1;
    float acc = 0.f;
    if (co < 70) {
        const float* wb = w + ((size_t)co * 64 + ci) * 9;
#pragma unroll
        for (int dy = 0; dy < 3; ++dy) {
            float my = M[py][dy][sy];
            if (my != 0.f)
#pragma unroll
                for (int dx = 0; dx < 3; ++dx) {
                    float mx = M[px][dx][sx];
                    if (mx != 0.f) acc += wb[dy * 3 + dx] * my * mx;
                }
        }
    }
    dst[idx] = f2b(acc);
}

// ===========================================================================
// img0/img1 (fp32 NCHW) -> s0in ch 0-5 (halo'd NHWC, CALLOC=72); zero ch6/7
// ===========================================================================
__global__ __launch_bounds__(256) void img_cat(
    const float* __restrict__ i0, const float* __restrict__ i1, u16* __restrict__ dst)
{
    int idx = blockIdx.x * 256 + threadIdx.x;
    if (idx >= 4 * 147456) return;
    int n = idx / 147456, r = idx - n * 147456;
    int y = r / 384, x = r - y * 384;
    u16* p = dst + ((size_t)n * 386 * 386 + (size_t)(y + 1) * 386 + (x + 1)) * 72;
#pragma unroll
    for (int c = 0; c < 3; ++c) {
        p[c]     = f2b(i0[((size_t)(n * 3 + c)) * 147456 + r]);
        p[3 + c] = f2b(i1[((size_t)(n * 3 + c)) * 147456 + r]);
    }
    p[6] = 0; p[7] = 0;
}

// ===========================================================================
// NCHW fp32 frame -> dense NHWC bf16 [total][C]
// ===========================================================================
__global__ __launch_bounds__(256) void t_nhwc(
    const float* __restrict__ src, u16* __restrict__ dst, int C, int HW, int total)
{
    int idx = blockIdx.x * 256 + threadIdx.x;
    if (idx >= total) return;
    int n = idx / HW, p = idx - n * HW;
    const float* s = src + (size_t)n * C * HW + p;
    u16* d = dst + (size_t)idx * C;
    for (int c8 = 0; c8 < C; c8 += 8) {
        s8v v;
#pragma unroll
        for (int i = 0; i < 8; ++i)
            v[i] = (short)f2b(s[(size_t)(c8 + i) * HW]);
        *(s8v*)(d + c8) = v;
    }
}

// ===========================================================================
// backward_warp from dense NHWC bf16 frame -> halo'd NHWC dst slot
// ===========================================================================
__global__ __launch_bounds__(256) void warp_nhwc(
    const u16* __restrict__ fr, const float* __restrict__ flow,
    u16* __restrict__ dst, int chb, int C, int H, int W, int CALLOC, int total)
{
    int HW = H * W;
    int idx = blockIdx.x * 256 + threadIdx.x;
    if (idx >= total) return;
    int n = idx / HW, r = idx - n * HW;
    int i = r / W, j = r - i * W;

    float fx = flow[((size_t)n * 2 + 0) * HW + r];
    float fy = flow[((size_t)n * 2 + 1) * HW + r];
    float x = (float)j + fx * ((float)W / (float)(W - 1));
    float y = (float)i + fy * ((float)H / (float)(H - 1));
    x = fminf(fmaxf(x, 0.f), (float)(W - 1));
    y = fminf(fmaxf(y, 0.f), (float)(H - 1));
    float x0f = floorf(x), y0f = floorf(y);
    int ix0 = (int)x0f, iy0 = (int)y0f;
    int ix1 = ix0 + 1; if (ix1 > W - 1) ix1 = W - 1;
    int iy1 = iy0 + 1; if (iy1 > H - 1) iy1 = H - 1;
    float wx = x - x0f, wy = y - y0f;
    float w00 = (1.f - wx) * (1.f - wy), w01 = wx * (1.f - wy);
    float w10 = (1.f - wx) * wy,         w11 = wx * wy;

    const u16* fb  = fr + (size_t)n * HW * C;
    const u16* p00 = fb + (size_t)(iy0 * W + ix0) * C;
    const u16* p01 = fb + (size_t)(iy0 * W + ix1) * C;
    const u16* p10 = fb + (size_t)(iy1 * W + ix0) * C;
    const u16* p11 = fb + (size_t)(iy1 * W + ix1) * C;
    u16* db = dst + ((size_t)n * (H + 2) * (W + 2) + (size_t)(i + 1) * (W + 2) + (j + 1)) * CALLOC + chb;

    for (int c8 = 0; c8 < C; c8 += 8) {
        s8v a = *(const s8v*)(p00 + c8);
        s8v b = *(const s8v*)(p01 + c8);
        s8v c = *(const s8v*)(p10 + c8);
        s8v d = *(const s8v*)(p11 + c8);
        s8v o;
#pragma unroll
        for (int t = 0; t < 8; ++t)
            o[t] = (short)f2b(w00 * b2f((u16)a[t]) + w01 * b2f((u16)b[t])
                            + w10 * b2f((u16)c[t]) + w11 * b2f((u16)d[t]));
        *(s8v*)(db + c8) = o;
    }
}

// ===========================================================================
// MFMA implicit-GEMM 3x3 conv.
//  SRC_MODE 0: halo'd NHWC (GLD16 fast path / reg tail)
//  SRC_MODE 1: fused 2x-bilinear-upsample of virtual concat [A | B]
//  SRC_MODE 3: two-source strided dense, REPLICATE-clamped coords, pure GLD16
//              (for parity-composed u2; branch-free pointer select keeps the
//               m104 linear-t discipline)
//  OUT_MODE 0: halo'd NHWC, 1: dense NHWC, 2: NCHW fp32,
//           3: halo'd NHWC at x2 stride (Y=2*row+pyo, X=2*col+pxo)
//  BORDER 1: blockIdx.x enumerates only border tiles (rows 0 / last, cols 0 / last)
// ===========================================================================
template<int CINP, int CHUNK, int CIN_ALLOC, int COUTP, int COUT, int STORE_LIM,
         int HO, int WO, int HT, int STRIDE, int RELU, int SRC_MODE, int OUT_MODE,
         int OCALLOC, int BORDER>
__global__ __launch_bounds__(256) void conv_k(
    const u16* __restrict__ srcA, const u16* __restrict__ srcB,
    long nsA, int rsA, int cA, long nsB, int rsB, int cB, int splitC,
    const u16* __restrict__ wt, const float* __restrict__ bias,
    void* __restrict__ outv, int pyo, int pxo)
{
    constexpr int WROWS = HT / 4;
    constexpr int ROWS  = (STRIDE == 1) ? HT + 2 : 2 * HT + 1;
    constexpr int COLS  = (STRIDE == 1) ? 18 : 33;
    constexpr int SUBS  = CHUNK / 8;
    constexpr int LSUB  = (SUBS == 8) ? 3 : 2;
    constexpr int XM    = SUBS - 1;
    constexpr int CH2   = CHUNK * 2;
    constexpr int NCHK  = CINP / CHUNK;
    constexpr int KK    = CHUNK / 32;
    constexpr int MT    = COUTP / 16;
    constexpr int NPX   = ROWS * COLS;
    constexpr int IN_B  = NPX * CH2;
    constexpr int W_B   = COUTP * CH2;
    constexpr int WI    = WO * STRIDE;
    constexpr int Hs    = HO / 2, Ws = WO / 2;
    constexpr long NSO  = (OUT_MODE == 0) ? (long)(HO + 2) * (WO + 2) * OCALLOC
                        : (OUT_MODE == 3) ? (long)(2 * HO + 2) * (2 * WO + 2) * OCALLOC
                                          : (long)HO * WO * OCALLOC;

    __shared__ s8v ldsv[(IN_B + 2 * W_B) / 16];
    char* lds  = (char*)ldsv;
    char* ldw0 = lds + IN_B;
    char* ldw1 = ldw0 + W_B;

    const int tid  = threadIdx.x;
    const int wv   = tid >> 6;
    const int lane = tid & 63;
    const int lr   = lane & 15;
    const int koct = lane >> 4;
    const int bx   = blockIdx.x, n = blockIdx.z;

    int tr, tc;
    if constexpr (BORDER) {
        constexpr int TC = WO / 16, TR = HO / HT;
        if (bx < TC)            { tr = 0;      tc = bx; }
        else if (bx < 2 * TC)   { tr = TR - 1; tc = bx - TC; }
        else { int b = bx - 2 * TC; tr = 1 + (b >> 1); tc = (b & 1) ? (TC - 1) : 0; }
    } else {
        tc = bx % (WO / 16); tr = bx / (WO / 16);
    }
    const int tx = tc * 16;
    const int ty = tr * HT;

    f4v acc[MT][WROWS];
#pragma unroll
    for (int m = 0; m < MT; ++m)
#pragma unroll
        for (int r = 0; r < WROWS; ++r) acc[m][r] = (f4v){0.f, 0.f, 0.f, 0.f};

    float bv[MT][4];
#pragma unroll
    for (int m = 0; m < MT; ++m)
#pragma unroll
        for (int j = 0; j < 4; ++j) {
            int co = m * 16 + koct * 4 + j;
            bv[m][j] = (co < COUT) ? bias[co] : 0.f;
        }

    for (int cig = 0; cig < NCHK; ++cig) {
        if (cig) __syncthreads();

        // ---------------- stage input chunk ----------------
        if constexpr (SRC_MODE == 0) {
            const u16* ns = srcA + (size_t)n * nsA;
            if (CIN_ALLOC >= CINP || (cig + 1) * CHUNK <= CIN_ALLOC) {
                for (int t = tid; t < NPX * SUBS; t += 256) {
                    int q = t >> LSUB, sub = t & XM;
                    int iy = q / COLS, ix = q - iy * COLS;
                    int xr = (STRIDE == 1) ? (q & XM) : ((q >> 1) & XM);
                    int ci0 = cig * CHUNK + (sub ^ xr) * 8;
                    const u16* g = ns + ((size_t)(ty * STRIDE + iy) * (WI + 2)
                                         + (tx * STRIDE + ix)) * CIN_ALLOC + ci0;
                    GLD16(g, lds + t * 16);
                }
            } else {
                for (int t = tid; t < NPX * SUBS; t += 256) {
                    int q = t >> LSUB, sub = t & XM;
                    int iy = q / COLS, ix = q - iy * COLS;
                    int xr = (STRIDE == 1) ? (q & XM) : ((q >> 1) & XM);
                    int ci0 = cig * CHUNK + (sub ^ xr) * 8;
                    s8v v = {0,0,0,0,0,0,0,0};
                    if (ci0 < CIN_ALLOC)
                        v = *(const s8v*)(ns + ((size_t)(ty * STRIDE + iy) * (WI + 2)
                                                + (tx * STRIDE + ix)) * CIN_ALLOC + ci0);
                    *(s8v*)(lds + t * 16) = v;
                }
            }
        } else if constexpr (SRC_MODE == 1) {   // fused up2x, integer bilinear
            for (int t = tid; t < NPX * SUBS; t += 256) {
                int q = t >> LSUB, sub = t & XM;
                int iy = q / COLS, ix = q - iy * COLS;
                int ssub = sub ^ (q & XM);
                int ci0 = cig * CHUNK + ssub * 8;
                int gy = ty + iy - 1, gx = tx + ix - 1;
                s8v val = {0,0,0,0,0,0,0,0};
                if ((unsigned)gy < (unsigned)HO && (unsigned)gx < (unsigned)WO) {
                    const u16* sp; int rs, cal, cof; long nss;
                    if (ci0 < splitC) { sp = srcA; nss = nsA; rs = rsA; cal = cA; cof = ci0; }
                    else              { sp = srcB; nss = nsB; rs = rsB; cal = cB; cof = ci0 - splitC; }
                    sp += (size_t)n * nss;
                    int y0 = (gy >> 1) + (gy & 1) - 1;
                    int x0 = (gx >> 1) + (gx & 1) - 1;
                    float wy = (gy & 1) ? 0.25f : 0.75f;
                    float wx = (gx & 1) ? 0.25f : 0.75f;
                    int y1 = min(y0 + 1, Hs - 1); y0 = max(y0, 0);
                    int x1 = min(x0 + 1, Ws - 1); x0 = max(x0, 0);
                    const s8v a = *(const s8v*)(sp + (size_t)y0 * rs + (size_t)x0 * cal + cof);
                    const s8v b = *(const s8v*)(sp + (size_t)y0 * rs + (size_t)x1 * cal + cof);
                    const s8v c = *(const s8v*)(sp + (size_t)y1 * rs + (size_t)x0 * cal + cof);
                    const s8v d = *(const s8v*)(sp + (size_t)y1 * rs + (size_t)x1 * cal + cof);
                    float w00 = (1.f - wx) * (1.f - wy), w01 = wx * (1.f - wy);
                    float w10 = (1.f - wx) * wy,         w11 = wx * wy;
#pragma unroll
                    for (int i = 0; i < 8; ++i) {
                        float v = w00 * b2f((u16)a[i]) + w01 * b2f((u16)b[i])
                                + w10 * b2f((u16)c[i]) + w11 * b2f((u16)d[i]);
                        val[i] = (short)f2b(v);
                    }
                }
                *(s8v*)(lds + t * 16) = val;
            }
        } else {   // SRC_MODE == 3: two-source strided, replicate-clamped, GLD16
            for (int t = tid; t < NPX * SUBS; t += 256) {
                int q = t >> LSUB, sub = t & XM;
                int iy = q / COLS, ix = q - iy * COLS;
                int xr = q & XM;
                int ci0 = cig * CHUNK + (sub ^ xr) * 8;
                int sy = min(max(ty + iy - 1, 0), HO - 1);
                int sx = min(max(tx + ix - 1, 0), WO - 1);
                const u16* g = (ci0 < splitC)
                    ? srcA + (size_t)n * nsA + (size_t)sy * rsA + (size_t)sx * cA + ci0
                    : srcB + (size_t)n * nsB + (size_t)sy * rsB + (size_t)sx * cB + (ci0 - splitC);
                GLD16(g, lds + t * 16);
            }
        }

        // ---------------- weight slice staging (double-buffered LDS) ------
        auto stageW = [&](int s, char* dstb) {
            for (int t = tid; t < COUTP * SUBS; t += 256) {
                int co = t >> LSUB, sub = t & XM;
                int ssub = sub ^ (co & XM);
                const u16* g = wt + ((size_t)(s * COUTP + co) * CINP + cig * CHUNK + ssub * 8);
                GLD16(g, dstb + t * 16);
            }
        };
        stageW(0, ldw0);

#pragma unroll
        for (int s = 0; s < 9; ++s) {
            __syncthreads();
            if (s < 8) stageW(s + 1, (s & 1) ? ldw0 : ldw1);
            char* wc = (s & 1) ? ldw1 : ldw0;
            const int dy = s / 3, dx = s - dy * 3;
#pragma unroll
            for (int kk = 0; kk < KK; ++kk) {
                const int koff = kk * 64 + koct * 16;
                s8v bfr[WROWS];
#pragma unroll
                for (int r = 0; r < WROWS; ++r) {
                    int orow = wv * WROWS + r;
                    int q, xr;
                    if (STRIDE == 1) { q = (orow + dy) * COLS + lr + dx; xr = q & XM; }
                    else             { q = (2 * orow + dy) * COLS + 2 * lr + dx; xr = (q >> 1) & XM; }
                    bfr[r] = *(const s8v*)(lds + q * CH2 + (koff ^ (xr << 4)));
                }
#pragma unroll
                for (int m = 0; m < MT; ++m) {
                    s8v afr = *(const s8v*)(wc + (m * 16 + lr) * CH2 + (koff ^ ((lr & XM) << 4)));
#pragma unroll
                    for (int r = 0; r < WROWS; ++r)
                        acc[m][r] = __builtin_amdgcn_mfma_f32_16x16x32_bf16(afr, bfr[r], acc[m][r], 0, 0, 0);
                }
            }
        }
    }

    // ---------------- epilogue ----------------
#pragma unroll
    for (int m = 0; m < MT; ++m) {
#pragma unroll
        for (int r = 0; r < WROWS; ++r) {
            int row = ty + wv * WROWS + r, col = tx + lr;
            float x0 = acc[m][r][0] + bv[m][0];
            float x1 = acc[m][r][1] + bv[m][1];
            float x2 = acc[m][r][2] + bv[m][2];
            float x3 = acc[m][r][3] + bv[m][3];
            if (RELU) {
                x0 = fmaxf(x0, 0.f); x1 = fmaxf(x1, 0.f);
                x2 = fmaxf(x2, 0.f); x3 = fmaxf(x3, 0.f);
            }
            int co0 = m * 16 + koct * 4;
            if constexpr (OUT_MODE == 2) {
                float* op = (float*)outv;
                float xs[4] = {x0, x1, x2, x3};
#pragma unroll
                for (int j = 0; j < 4; ++j)
                    if (co0 + j < STORE_LIM)
                        op[((size_t)(n * 4 + co0 + j) * HO + row) * WO + col] = xs[j];
            } else {
                size_t pix;
                if constexpr (OUT_MODE == 0)
                    pix = (size_t)(row + 1) * (WO + 2) + (col + 1);
                else if constexpr (OUT_MODE == 3)
                    pix = (size_t)(2 * row + pyo + 1) * (2 * WO + 2) + (2 * col + pxo + 1);
                else
                    pix = (size_t)row * WO + col;
                u16* ob = (u16*)outv + (size_t)n * NSO + pix * OCALLOC + co0;
                if (co0 + 3 < STORE_LIM) {
                    unsigned lo = (unsigned)f2b(x0) | ((unsigned)f2b(x1) << 16);
                    unsigned hi = (unsigned)f2b(x2) | ((unsigned)f2b(x3) << 16);
                    *(u2v*)ob = (u2v){lo, hi};
                } else {
                    float xs[4] = {x0, x1, x2, x3};
#pragma unroll
                    for (int j = 0; j < 4; ++j)
                        if (co0 + j < STORE_LIM) ob[j] = f2b(xs[j]);
                }
            }
        }
    }
}

// ===========================================================================
extern "C" void kernel_launch(void* const* d_in, const int* in_sizes, int n_in,
                              void* d_out, int out_size, void* d_ws, size_t ws_size,
                              hipStream_t stream)
{
    const float* img0  = (const float*)d_in[0];
    const float* img1  = (const float*)d_in[1];
    const float* ft0   = (const float*)d_in[2];
    const float* ft1   = (const float*)d_in[3];
    const float* ft0s2 = (const float*)d_in[4];
    const float* ft1s2 = (const float*)d_in[5];
    const float* ft0s4 = (const float*)d_in[6];
    const float* ft1s4 = (const float*)d_in[7];
    const float* c0_0  = (const float*)d_in[8];
    const float* c0_1  = (const float*)d_in[9];
    const float* c0_2  = (const float*)d_in[10];
    const float* c1_0  = (const float*)d_in[11];
    const float* c1_1  = (const float*)d_in[12];
    const float* c1_2  = (const float*)d_in[13];
    const float* wd0a = (const float*)d_in[14]; const float* bd0a = (const float*)d_in[15];
    const float* wd0b = (const float*)d_in[16]; const float* bd0b = (const float*)d_in[17];
    const float* wd1a = (const float*)d_in[18]; const float* bd1a = (const float*)d_in[19];
    const float* wd1b = (const float*)d_in[20]; const float* bd1b = (const float*)d_in[21];
    const float* wd2a = (const float*)d_in[22]; const float* bd2a = (const float*)d_in[23];
    const float* wd2b = (const float*)d_in[24]; const float* bd2b = (const float*)d_in[25];
    const float* wu0  = (const float*)d_in[26]; const float* bu0  = (const float*)d_in[27];
    const float* wu1  = (const float*)d_in[28]; const float* bu1  = (const float*)d_in[29];
    const float* wu2  = (const float*)d_in[30]; const float* bu2  = (const float*)d_in[31];
    const float* wfin = (const float*)d_in[32]; const float* bfin = (const float*)d_in[33];

    u16* ws = (u16*)d_ws;
    // region plan (bf16 elems, total 86,314,880 = 172.6 MB — proven)
    u16* s0in = ws + 0;          // 4 x 386x386 x 72 (dead after d0a)
    u16* x2   = ws + 0;          // halo'd, same geometry (u2 output; halo stays 0)
    u16* s1in = ws + 42913152;   // 4 x 194x194 x 128
    u16* scrB = ws + 42913152;   // 384-level warp scratch (dead before d0b)
    u16* s2in = ws + 62182784;   // 4 x 98x98 x 192
    u16* scr  = ws + 69558656;   // 192/96-level warp scratch (aliases t0/t1)
    u16* t0   = ws + 69558656;   // 4 x 194x194 x 32 (dead after d0b)
    u16* Ku2  = ws + 69558656;   // composed u2 weights [4][9][80][64] (184,320; in dead t0)
    u16* t1   = ws + 74376064;   // 4 x 98x98 x 64
    u16* t2   = ws + 76834688;   // 4 x 50x50 x 96
    u16* s2b  = ws + 77794688;   // 4 x 48x48 x 96 (dense)
    u16* x0   = ws + 78679424;   // 4 x 96x96 x 64 (dense)
    u16* x1   = ws + 81038720;   // 4 x 192x192 x 32 (dense)
    u16* wtb  = ws + 85757312;
    u16* Wd0a = wtb;
    u16* Wd0b = Wd0a + 27648;
    u16* Wd1a = Wd0b + 9216;
    u16* Wd1b = Wd1a + 73728;
    u16* Wd2a = Wd1b + 36864;
    u16* Wd2b = Wd2a + 165888;
    u16* Wu0  = Wd2b + 82944;
    u16* Wu1  = Wu0 + 55296;
    u16* Wu2  = Wu1 + 36864;
    u16* Wfin = Wu2 + 46080;

    const int HW384 = 147456, HW192 = 36864, HW96 = 9216;

    // ---- 1) warp stage FIRST (scratch aliases t0/t1 + s1in)
    for (int f = 0; f < 2; ++f) {
        t_nhwc<<<DIV_UP(4 * HW384, 256), 256, 0, stream>>>(
            f ? c1_0 : c0_0, scrB, 32, HW384, 4 * HW384);
        warp_nhwc<<<DIV_UP(4 * HW384, 256), 256, 0, stream>>>(
            scrB, f ? ft1 : ft0, s0in, f ? 40 : 8, 32, 384, 384, 72, 4 * HW384);
    }
    for (int f = 0; f < 2; ++f) {
        t_nhwc<<<DIV_UP(4 * HW192, 256), 256, 0, stream>>>(
            f ? c1_1 : c0_1, scr, 48, HW192, 4 * HW192);
        warp_nhwc<<<DIV_UP(4 * HW192, 256), 256, 0, stream>>>(
            scr, f ? ft1s2 : ft0s2, s1in, f ? 80 : 32, 48, 192, 192, 128, 4 * HW192);
    }
    for (int f = 0; f < 2; ++f) {
        t_nhwc<<<DIV_UP(4 * HW96, 256), 256, 0, stream>>>(
            f ? c1_2 : c0_2, scr, 64, HW96, 4 * HW96);
        warp_nhwc<<<DIV_UP(4 * HW96, 256), 256, 0, stream>>>(
            scr, f ? ft1s4 : ft0s4, s2in, f ? 128 : 64, 64, 96, 96, 192, 4 * HW96);
    }

    // ---- 2) halo rings
    HZ6 hz = {{ {s0in, 384, 384, 72}, {s1in, 192, 192, 128}, {s2in, 96, 96, 192},
                {t0, 192, 192, 32},   {t1, 96, 96, 64},      {t2, 48, 48, 96} }};
    halo_zero<<<dim3(DIV_UP(4 * 386 * 386, 256), 6), 256, 0, stream>>>(hz);

    // ---- 3) weight transposes + img concat
    WT10 wt = {{ {wd0a, Wd0a, 32, 70, 32, 96, 1},  {wd0b, Wd0b, 32, 32, 32, 32, 0},
                 {wd1a, Wd1a, 64, 128, 64, 128, 0},{wd1b, Wd1b, 64, 64, 64, 64, 0},
                 {wd2a, Wd2a, 96, 192, 96, 192, 0},{wd2b, Wd2b, 96, 96, 96, 96, 0},
                 {wu0,  Wu0,  64, 96, 64, 96, 0},  {wu1,  Wu1,  32, 128, 32, 128, 0},
                 {wu2,  Wu2,  70, 64, 80, 64, 0},  {wfin, Wfin, 4, 70, 16, 96, 0} }};
    wtrans<<<dim3(DIV_UP(9 * 96 * 192, 256), 10), 256, 0, stream>>>(wt);

    img_cat<<<DIV_UP(4 * 147456, 256), 256, 0, stream>>>(img0, img1, s0in);

    // ---- down0
    conv_k<96,32,72, 32,32,32, 192,192,4,2,1, 0,0,32,0>
        <<<dim3(12*48,1,4),256,0,stream>>>(s0in,nullptr, 386L*386*72,0,0, 0,0,0,0, Wd0a,bd0a,t0, 0,0);
    conv_k<32,32,32, 32,32,32, 192,192,8,1,1, 0,0,128,0>
        <<<dim3(12*24,1,4),256,0,stream>>>(t0,nullptr, 194L*194*32,0,0, 0,0,0,0, Wd0b,bd0b,s1in, 0,0);

    // ---- composed u2 weights (t0 now dead)
    wtrans2<<<DIV_UP(4*9*80*64, 256), 256, 0, stream>>>(wu2, Ku2);

    // ---- down1
    conv_k<128,32,128, 64,64,64, 96,96,4,2,1, 0,0,64,0>
        <<<dim3(6*24,1,4),256,0,stream>>>(s1in,nullptr, 194L*194*128,0,0, 0,0,0,0, Wd1a,bd1a,t1, 0,0);
    conv_k<64,64,64, 64,64,64, 96,96,4,1,1, 0,0,192,0>
        <<<dim3(6*24,1,4),256,0,stream>>>(t1,nullptr, 98L*98*64,0,0, 0,0,0,0, Wd1b,bd1b,s2in, 0,0);

    // ---- down2
    conv_k<192,32,192, 96,96,96, 48,48,4,2,1, 0,0,96,0>
        <<<dim3(3*12,1,4),256,0,stream>>>(s2in,nullptr, 98L*98*192,0,0, 0,0,0,0, Wd2a,bd2a,t2, 0,0);
    conv_k<96,32,96, 96,96,96, 48,48,4,1,1, 0,1,96,0>
        <<<dim3(3*12,1,4),256,0,stream>>>(t2,nullptr, 50L*50*96,0,0, 0,0,0,0, Wd2b,bd2b,s2b, 0,0);

    // ---- decoder: u0/u1 fused (verified)
    conv_k<96,32,96, 64,64,64, 96,96,4,1,1, 1,1,64,0>
        <<<dim3(6*24,1,4),256,0,stream>>>(s2b,s2b, 48L*48*96,48*96,96, 48L*48*96,48*96,96, 96,
                                          Wu0,bu0,x0, 0,0);
    conv_k<128,64,128, 32,32,32, 192,192,8,1,1, 1,1,32,0>
        <<<dim3(12*24,1,4),256,0,stream>>>(x0, s2in + (size_t)(98+1)*192,
                                           96L*96*64,96*64,64, 98L*98*192,98*192,192, 64,
                                           Wu1,bu1,x1, 0,0);

    // ---- u2: 4 parity-composed convs on the 192² source (replicate-clamped
    //      GLD16 staging; interior exact), then fused-path fix on border tiles
    for (int p = 0; p < 4; ++p) {
        conv_k<64,64,64, 80,70,70, 192,192,8,1,1, 3,3,72,0>
            <<<dim3(12*24,1,4),256,0,stream>>>(
                x1, s1in + (size_t)(194+1)*128,
                192L*192*32, 192*32, 32, 194L*194*128, 194*128, 128, 32,
                Ku2 + (size_t)p * 46080, bu2, x2, p >> 1, p & 1);
    }
    conv_k<64,64,64, 80,70,70, 384,384,8,1,1, 1,0,72,1>
        <<<dim3(140,1,4),256,0,stream>>>(x1, s1in + (size_t)(194+1)*128,
                                         192L*192*32,192*32,32, 194L*194*128,194*128,128, 32,
                                         Wu2,bu2,x2, 0,0);

    // ---- final conv (halo'd x2, GLD16 fast path + reg tail), HT=8, fp32 out
    conv_k<96,32,72, 16,4,4, 384,384,8,1,0, 0,2,0,0>
        <<<dim3(24*48,1,4),256,0,stream>>>(x2,nullptr, 386L*386*72,0,0, 0,0,0,0, Wfin,bfin,d_out, 0,0);
}

// Round 17
// 704.474 us; speedup vs baseline: 1.1043x; 1.1043x over previous
//
#include <hip/hip_runtime.h>

#define DIV_UP(a,b) (((a)+(b)-1)/(b))

typedef unsigned short u16;
typedef __attribute__((ext_vector_type(8))) short s8v;
typedef __attribute__((ext_vector_type(4))) float f4v;
typedef __attribute__((ext_vector_type(2))) unsigned int u2v;

__device__ __forceinline__ float b2f(u16 x) {
    return __uint_as_float(((unsigned)x) << 16);
}
__device__ __forceinline__ u16 f2b(float f) {
    unsigned u = __float_as_uint(f);
    return (u16)((u + 0x7FFFu + ((u >> 16) & 1u)) >> 16);
}

#define GLD16(gp, lp) __builtin_amdgcn_global_load_lds( \
    (const __attribute__((address_space(1))) unsigned int*)(gp), \
    (__attribute__((address_space(3))) unsigned int*)(lp), 16, 0, 0)

// ===========================================================================
// combined halo zero: 6 halo'd NHWC buffers (runs AFTER warp stage)
// ===========================================================================
struct HZ { u16* p; int H, W, C; };
struct HZ6 { HZ d[6]; };
__global__ __launch_bounds__(256) void halo_zero(HZ6 Z)
{
    HZ d = Z.d[blockIdx.y];
    int pw = d.W + 2, ph = d.H + 2;
    int tot = 4 * ph * pw;
    int idx = blockIdx.x * 256 + threadIdx.x;
    if (idx >= tot) return;
    int r = idx % (ph * pw);
    int y = r / pw, x = r - y * pw;
    if (y > 0 && y <= d.H && x > 0 && x <= d.W) return;
    u16* p = d.p + (size_t)idx * d.C;
    s8v z = {0,0,0,0,0,0,0,0};
    for (int c = 0; c < d.C; c += 8) *(s8v*)(p + c) = z;
}

// ===========================================================================
// weight transpose: W[Cout][Cin][3][3] f32 -> W'[9][COUTP][CINP] bf16
// CINP MUST match conv's CINP (round-7 lesson). shift=1: s0in ch remap.
// ===========================================================================
struct WT { const float* src; u16* dst; int Cout, Cin, COUTP, CINP, shift; };
struct WT10 { WT d[10]; };
__global__ __launch_bounds__(256) void wtrans(WT10 Z)
{
    WT d = Z.d[blockIdx.y];
    int tot = 9 * d.COUTP * d.CINP;
    int idx = blockIdx.x * 256 + threadIdx.x;
    if (idx >= tot) return;
    int s = idx / (d.COUTP * d.CINP);
    int r = idx - s * (d.COUTP * d.CINP);
    int co = r / d.CINP, ci = r - co * d.CINP;
    int sci = ci;
    bool ok = (co < d.Cout);
    if (d.shift) {
        if (ci < 6)                 sci = ci;
        else if (ci >= 8 && ci < 72) sci = ci - 2;
        else                        ok = false;
    }
    ok = ok && (sci < d.Cin);
    float v = ok ? d.src[((size_t)co * d.Cin + sci) * 9 + s] : 0.f;
    d.dst[idx] = f2b(v);
}

// ===========================================================================
// NCHW fp32 frame (32ch, batch-pair base) -> interleaved NHWC bf16 [2HW][64]
// at channel offset cofs (frame0 -> 0, frame1 -> 32).
// ===========================================================================
__global__ __launch_bounds__(256) void t_nhwc64(
    const float* __restrict__ src, u16* __restrict__ dst,
    int HW, int total, int cofs)
{
    int idx = blockIdx.x * 256 + threadIdx.x;
    if (idx >= total) return;
    int n = idx / HW, p = idx - n * HW;
    const float* s = src + (size_t)n * 32 * HW + p;
    u16* d = dst + (size_t)idx * 64 + cofs;
#pragma unroll
    for (int c8 = 0; c8 < 32; c8 += 8) {
        s8v v;
#pragma unroll
        for (int i = 0; i < 8; ++i)
            v[i] = (short)f2b(s[(size_t)(c8 + i) * HW]);
        *(s8v*)(d + c8) = v;
    }
}

// ===========================================================================
// fused 384-level glue: img channels + BOTH frame warps per pixel, one
// contiguous 144B store (write-combined; replaces img_cat + 2x warp_nhwc).
// fr2: [2HW][64] (frame0 ch0-31, frame1 ch32-63). All float ptrs batch-pair
// offset. dst: s0in + n0*386*386*72.
// ===========================================================================
__global__ __launch_bounds__(256) void warp_full(
    const u16* __restrict__ fr2,
    const float* __restrict__ i0, const float* __restrict__ i1,
    const float* __restrict__ fl0, const float* __restrict__ fl1,
    u16* __restrict__ dst, int total)
{
    const int HW = 147456, W = 384, H = 384;
    int idx = blockIdx.x * 256 + threadIdx.x;
    if (idx >= total) return;
    int n = idx / HW, r = idx - n * HW;
    int i = r / W, j = r - i * W;

    s8v ov[9];
#pragma unroll
    for (int c = 0; c < 3; ++c) {
        ov[0][c]     = (short)f2b(i0[((size_t)(n * 3 + c)) * HW + r]);
        ov[0][3 + c] = (short)f2b(i1[((size_t)(n * 3 + c)) * HW + r]);
    }
    ov[0][6] = 0; ov[0][7] = 0;

#pragma unroll
    for (int f = 0; f < 2; ++f) {
        const float* flow = f ? fl1 : fl0;
        float fx = flow[((size_t)(n * 2 + 0)) * HW + r];
        float fy = flow[((size_t)(n * 2 + 1)) * HW + r];
        float x = (float)j + fx * ((float)W / (float)(W - 1));
        float y = (float)i + fy * ((float)H / (float)(H - 1));
        x = fminf(fmaxf(x, 0.f), (float)(W - 1));
        y = fminf(fmaxf(y, 0.f), (float)(H - 1));
        float x0f = floorf(x), y0f = floorf(y);
        int ix0 = (int)x0f, iy0 = (int)y0f;
        int ix1 = ix0 + 1; if (ix1 > W - 1) ix1 = W - 1;
        int iy1 = iy0 + 1; if (iy1 > H - 1) iy1 = H - 1;
        float wx = x - x0f, wy = y - y0f;
        float w00 = (1.f - wx) * (1.f - wy), w01 = wx * (1.f - wy);
        float w10 = (1.f - wx) * wy,         w11 = wx * wy;

        const u16* fb  = fr2 + (size_t)n * HW * 64 + 32 * f;
        const u16* p00 = fb + (size_t)(iy0 * W + ix0) * 64;
        const u16* p01 = fb + (size_t)(iy0 * W + ix1) * 64;
        const u16* p10 = fb + (size_t)(iy1 * W + ix0) * 64;
        const u16* p11 = fb + (size_t)(iy1 * W + ix1) * 64;

#pragma unroll
        for (int c8 = 0; c8 < 32; c8 += 8) {
            s8v a = *(const s8v*)(p00 + c8);
            s8v b = *(const s8v*)(p01 + c8);
            s8v c = *(const s8v*)(p10 + c8);
            s8v d = *(const s8v*)(p11 + c8);
#pragma unroll
            for (int t = 0; t < 8; ++t) {
                int ch = 8 + 32 * f + c8 + t;
                ov[ch >> 3][ch & 7] =
                    (short)f2b(w00 * b2f((u16)a[t]) + w01 * b2f((u16)b[t])
                             + w10 * b2f((u16)c[t]) + w11 * b2f((u16)d[t]));
            }
        }
    }

    u16* db = dst + ((size_t)n * 386 * 386 + (size_t)(i + 1) * 386 + (j + 1)) * 72;
#pragma unroll
    for (int k = 0; k < 9; ++k) *(s8v*)(db + 8 * k) = ov[k];
}

// ===========================================================================
// NCHW fp32 frame -> dense NHWC bf16 [total][C]  (192/96 levels)
// ===========================================================================
__global__ __launch_bounds__(256) void t_nhwc(
    const float* __restrict__ src, u16* __restrict__ dst, int C, int HW, int total)
{
    int idx = blockIdx.x * 256 + threadIdx.x;
    if (idx >= total) return;
    int n = idx / HW, p = idx - n * HW;
    const float* s = src + (size_t)n * C * HW + p;
    u16* d = dst + (size_t)idx * C;
    for (int c8 = 0; c8 < C; c8 += 8) {
        s8v v;
#pragma unroll
        for (int i = 0; i < 8; ++i)
            v[i] = (short)f2b(s[(size_t)(c8 + i) * HW]);
        *(s8v*)(d + c8) = v;
    }
}

// ===========================================================================
// backward_warp from dense NHWC bf16 frame -> halo'd NHWC dst slot (192/96)
// ===========================================================================
__global__ __launch_bounds__(256) void warp_nhwc(
    const u16* __restrict__ fr, const float* __restrict__ flow,
    u16* __restrict__ dst, int chb, int C, int H, int W, int CALLOC, int total)
{
    int HW = H * W;
    int idx = blockIdx.x * 256 + threadIdx.x;
    if (idx >= total) return;
    int n = idx / HW, r = idx - n * HW;
    int i = r / W, j = r - i * W;

    float fx = flow[((size_t)n * 2 + 0) * HW + r];
    float fy = flow[((size_t)n * 2 + 1) * HW + r];
    float x = (float)j + fx * ((float)W / (float)(W - 1));
    float y = (float)i + fy * ((float)H / (float)(H - 1));
    x = fminf(fmaxf(x, 0.f), (float)(W - 1));
    y = fminf(fmaxf(y, 0.f), (float)(H - 1));
    float x0f = floorf(x), y0f = floorf(y);
    int ix0 = (int)x0f, iy0 = (int)y0f;
    int ix1 = ix0 + 1; if (ix1 > W - 1) ix1 = W - 1;
    int iy1 = iy0 + 1; if (iy1 > H - 1) iy1 = H - 1;
    float wx = x - x0f, wy = y - y0f;
    float w00 = (1.f - wx) * (1.f - wy), w01 = wx * (1.f - wy);
    float w10 = (1.f - wx) * wy,         w11 = wx * wy;

    const u16* fb  = fr + (size_t)n * HW * C;
    const u16* p00 = fb + (size_t)(iy0 * W + ix0) * C;
    const u16* p01 = fb + (size_t)(iy0 * W + ix1) * C;
    const u16* p10 = fb + (size_t)(iy1 * W + ix0) * C;
    const u16* p11 = fb + (size_t)(iy1 * W + ix1) * C;
    u16* db = dst + ((size_t)n * (H + 2) * (W + 2) + (size_t)(i + 1) * (W + 2) + (j + 1)) * CALLOC + chb;

    for (int c8 = 0; c8 < C; c8 += 8) {
        s8v a = *(const s8v*)(p00 + c8);
        s8v b = *(const s8v*)(p01 + c8);
        s8v c = *(const s8v*)(p10 + c8);
        s8v d = *(const s8v*)(p11 + c8);
        s8v o;
#pragma unroll
        for (int t = 0; t < 8; ++t)
            o[t] = (short)f2b(w00 * b2f((u16)a[t]) + w01 * b2f((u16)b[t])
                            + w10 * b2f((u16)c[t]) + w11 * b2f((u16)d[t]));
        *(s8v*)(db + c8) = o;
    }
}

// ===========================================================================
// MFMA implicit-GEMM 3x3 conv — round-15 verified structure (GLD16 input
// staging + double-buffered weight LDS; integer-parity bilinear SRC_MODE=1).
//  SRC_MODE 0: halo'd NHWC
//  SRC_MODE 1: fused 2x-bilinear-upsample of virtual concat [A | B]
//  OUT_MODE 0: halo'd NHWC, 1: dense NHWC, 2: NCHW fp32
// ===========================================================================
template<int CINP, int CHUNK, int CIN_ALLOC, int COUTP, int COUT, int STORE_LIM,
         int HO, int WO, int HT, int STRIDE, int RELU, int SRC_MODE, int OUT_MODE, int OCALLOC>
__global__ __launch_bounds__(256) void conv_k(
    const u16* __restrict__ srcA, const u16* __restrict__ srcB,
    long nsA, int rsA, int cA, long nsB, int rsB, int cB, int splitC,
    const u16* __restrict__ wt, const float* __restrict__ bias,
    void* __restrict__ outv)
{
    constexpr int WROWS = HT / 4;
    constexpr int ROWS  = (STRIDE == 1) ? HT + 2 : 2 * HT + 1;
    constexpr int COLS  = (STRIDE == 1) ? 18 : 33;
    constexpr int SUBS  = CHUNK / 8;
    constexpr int LSUB  = (SUBS == 8) ? 3 : 2;
    constexpr int XM    = SUBS - 1;
    constexpr int CH2   = CHUNK * 2;
    constexpr int NCHK  = CINP / CHUNK;
    constexpr int KK    = CHUNK / 32;
    constexpr int MT    = COUTP / 16;
    constexpr int NPX   = ROWS * COLS;
    constexpr int IN_B  = NPX * CH2;
    constexpr int W_B   = COUTP * CH2;
    constexpr int WI    = WO * STRIDE;
    constexpr int Hs    = HO / 2, Ws = WO / 2;
    constexpr long NSO  = (OUT_MODE == 0) ? (long)(HO + 2) * (WO + 2) * OCALLOC
                                          : (long)HO * WO * OCALLOC;

    __shared__ s8v ldsv[(IN_B + 2 * W_B) / 16];
    char* lds  = (char*)ldsv;
    char* ldw0 = lds + IN_B;
    char* ldw1 = ldw0 + W_B;

    const int tid  = threadIdx.x;
    const int wv   = tid >> 6;
    const int lane = tid & 63;
    const int lr   = lane & 15;
    const int koct = lane >> 4;
    const int bx   = blockIdx.x, n = blockIdx.z;
    const int tx   = (bx % (WO / 16)) * 16;
    const int ty   = (bx / (WO / 16)) * HT;

    f4v acc[MT][WROWS];
#pragma unroll
    for (int m = 0; m < MT; ++m)
#pragma unroll
        for (int r = 0; r < WROWS; ++r) acc[m][r] = (f4v){0.f, 0.f, 0.f, 0.f};

    float bv[MT][4];
#pragma unroll
    for (int m = 0; m < MT; ++m)
#pragma unroll
        for (int j = 0; j < 4; ++j) {
            int co = m * 16 + koct * 4 + j;
            bv[m][j] = (co < COUT) ? bias[co] : 0.f;
        }

    for (int cig = 0; cig < NCHK; ++cig) {
        if (cig) __syncthreads();

        // ---------------- stage input chunk ----------------
        if constexpr (SRC_MODE == 0) {
            const u16* ns = srcA + (size_t)n * nsA;
            if (CIN_ALLOC >= CINP || (cig + 1) * CHUNK <= CIN_ALLOC) {
                for (int t = tid; t < NPX * SUBS; t += 256) {
                    int q = t >> LSUB, sub = t & XM;
                    int iy = q / COLS, ix = q - iy * COLS;
                    int xr = (STRIDE == 1) ? (q & XM) : ((q >> 1) & XM);
                    int ci0 = cig * CHUNK + (sub ^ xr) * 8;
                    const u16* g = ns + ((size_t)(ty * STRIDE + iy) * (WI + 2)
                                         + (tx * STRIDE + ix)) * CIN_ALLOC + ci0;
                    GLD16(g, lds + t * 16);
                }
            } else {
                for (int t = tid; t < NPX * SUBS; t += 256) {
                    int q = t >> LSUB, sub = t & XM;
                    int iy = q / COLS, ix = q - iy * COLS;
                    int xr = (STRIDE == 1) ? (q & XM) : ((q >> 1) & XM);
                    int ci0 = cig * CHUNK + (sub ^ xr) * 8;
                    s8v v = {0,0,0,0,0,0,0,0};
                    if (ci0 < CIN_ALLOC)
                        v = *(const s8v*)(ns + ((size_t)(ty * STRIDE + iy) * (WI + 2)
                                                + (tx * STRIDE + ix)) * CIN_ALLOC + ci0);
                    *(s8v*)(lds + t * 16) = v;
                }
            }
        } else {   // SRC_MODE == 1: fused up2x of [A | B], integer bilinear
            for (int t = tid; t < NPX * SUBS; t += 256) {
                int q = t >> LSUB, sub = t & XM;
                int iy = q / COLS, ix = q - iy * COLS;
                int ssub = sub ^ (q & XM);
                int ci0 = cig * CHUNK + ssub * 8;
                int gy = ty + iy - 1, gx = tx + ix - 1;
                s8v val = {0,0,0,0,0,0,0,0};
                if ((unsigned)gy < (unsigned)HO && (unsigned)gx < (unsigned)WO) {
                    const u16* sp; int rs, cal, cof; long nss;
                    if (ci0 < splitC) { sp = srcA; nss = nsA; rs = rsA; cal = cA; cof = ci0; }
                    else              { sp = srcB; nss = nsB; rs = rsB; cal = cB; cof = ci0 - splitC; }
                    sp += (size_t)n * nss;
                    int y0 = (gy >> 1) + (gy & 1) - 1;
                    int x0 = (gx >> 1) + (gx & 1) - 1;
                    float wy = (gy & 1) ? 0.25f : 0.75f;
                    float wx = (gx & 1) ? 0.25f : 0.75f;
                    int y1 = min(y0 + 1, Hs - 1); y0 = max(y0, 0);
                    int x1 = min(x0 + 1, Ws - 1); x0 = max(x0, 0);
                    const s8v a = *(const s8v*)(sp + (size_t)y0 * rs + (size_t)x0 * cal + cof);
                    const s8v b = *(const s8v*)(sp + (size_t)y0 * rs + (size_t)x1 * cal + cof);
                    const s8v c = *(const s8v*)(sp + (size_t)y1 * rs + (size_t)x0 * cal + cof);
                    const s8v d = *(const s8v*)(sp + (size_t)y1 * rs + (size_t)x1 * cal + cof);
                    float w00 = (1.f - wx) * (1.f - wy), w01 = wx * (1.f - wy);
                    float w10 = (1.f - wx) * wy,         w11 = wx * wy;
#pragma unroll
                    for (int i = 0; i < 8; ++i) {
                        float v = w00 * b2f((u16)a[i]) + w01 * b2f((u16)b[i])
                                + w10 * b2f((u16)c[i]) + w11 * b2f((u16)d[i]);
                        val[i] = (short)f2b(v);
                    }
                }
                *(s8v*)(lds + t * 16) = val;
            }
        }

        // ---------------- weight slice staging (double-buffered LDS) ------
        auto stageW = [&](int s, char* dstb) {
            for (int t = tid; t < COUTP * SUBS; t += 256) {
                int co = t >> LSUB, sub = t & XM;
                int ssub = sub ^ (co & XM);
                const u16* g = wt + ((size_t)(s * COUTP + co) * CINP + cig * CHUNK + ssub * 8);
                GLD16(g, dstb + t * 16);
            }
        };
        stageW(0, ldw0);

#pragma unroll
        for (int s = 0; s < 9; ++s) {
            __syncthreads();
            if (s < 8) stageW(s + 1, (s & 1) ? ldw0 : ldw1);
            char* wc = (s & 1) ? ldw1 : ldw0;
            const int dy = s / 3, dx = s - dy * 3;
#pragma unroll
            for (int kk = 0; kk < KK; ++kk) {
                const int koff = kk * 64 + koct * 16;
                s8v bfr[WROWS];
#pragma unroll
                for (int r = 0; r < WROWS; ++r) {
                    int orow = wv * WROWS + r;
                    int q, xr;
                    if (STRIDE == 1) { q = (orow + dy) * COLS + lr + dx; xr = q & XM; }
                    else             { q = (2 * orow + dy) * COLS + 2 * lr + dx; xr = (q >> 1) & XM; }
                    bfr[r] = *(const s8v*)(lds + q * CH2 + (koff ^ (xr << 4)));
                }
#pragma unroll
                for (int m = 0; m < MT; ++m) {
                    s8v afr = *(const s8v*)(wc + (m * 16 + lr) * CH2 + (koff ^ ((lr & XM) << 4)));
#pragma unroll
                    for (int r = 0; r < WROWS; ++r)
                        acc[m][r] = __builtin_amdgcn_mfma_f32_16x16x32_bf16(afr, bfr[r], acc[m][r], 0, 0, 0);
                }
            }
        }
    }

    // ---------------- epilogue ----------------
#pragma unroll
    for (int m = 0; m < MT; ++m) {
#pragma unroll
        for (int r = 0; r < WROWS; ++r) {
            int row = ty + wv * WROWS + r, col = tx + lr;
            float x0 = acc[m][r][0] + bv[m][0];
            float x1 = acc[m][r][1] + bv[m][1];
            float x2 = acc[m][r][2] + bv[m][2];
            float x3 = acc[m][r][3] + bv[m][3];
            if (RELU) {
                x0 = fmaxf(x0, 0.f); x1 = fmaxf(x1, 0.f);
                x2 = fmaxf(x2, 0.f); x3 = fmaxf(x3, 0.f);
            }
            int co0 = m * 16 + koct * 4;
            if constexpr (OUT_MODE == 2) {
                float* op = (float*)outv;
                float xs[4] = {x0, x1, x2, x3};
#pragma unroll
                for (int j = 0; j < 4; ++j)
                    if (co0 + j < STORE_LIM)
                        op[((size_t)(n * 4 + co0 + j) * HO + row) * WO + col] = xs[j];
            } else {
                size_t pix = (OUT_MODE == 0)
                    ? ((size_t)(row + 1) * (WO + 2) + (col + 1))
                    : ((size_t)row * WO + col);
                u16* ob = (u16*)outv + (size_t)n * NSO + pix * OCALLOC + co0;
                if (co0 + 3 < STORE_LIM) {
                    unsigned lo = (unsigned)f2b(x0) | ((unsigned)f2b(x1) << 16);
                    unsigned hi = (unsigned)f2b(x2) | ((unsigned)f2b(x3) << 16);
                    *(u2v*)ob = (u2v){lo, hi};
                } else {
                    float xs[4] = {x0, x1, x2, x3};
#pragma unroll
                    for (int j = 0; j < 4; ++j)
                        if (co0 + j < STORE_LIM) ob[j] = f2b(xs[j]);
                }
            }
        }
    }
}

// ===========================================================================
extern "C" void kernel_launch(void* const* d_in, const int* in_sizes, int n_in,
                              void* d_out, int out_size, void* d_ws, size_t ws_size,
                              hipStream_t stream)
{
    const float* img0  = (const float*)d_in[0];
    const float* img1  = (const float*)d_in[1];
    const float* ft0   = (const float*)d_in[2];
    const float* ft1   = (const float*)d_in[3];
    const float* ft0s2 = (const float*)d_in[4];
    const float* ft1s2 = (const float*)d_in[5];
    const float* ft0s4 = (const float*)d_in[6];
    const float* ft1s4 = (const float*)d_in[7];
    const float* c0_0  = (const float*)d_in[8];
    const float* c0_1  = (const float*)d_in[9];
    const float* c0_2  = (const float*)d_in[10];
    const float* c1_0  = (const float*)d_in[11];
    const float* c1_1  = (const float*)d_in[12];
    const float* c1_2  = (const float*)d_in[13];
    const float* wd0a = (const float*)d_in[14]; const float* bd0a = (const float*)d_in[15];
    const float* wd0b = (const float*)d_in[16]; const float* bd0b = (const float*)d_in[17];
    const float* wd1a = (const float*)d_in[18]; const float* bd1a = (const float*)d_in[19];
    const float* wd1b = (const float*)d_in[20]; const float* bd1b = (const float*)d_in[21];
    const float* wd2a = (const float*)d_in[22]; const float* bd2a = (const float*)d_in[23];
    const float* wd2b = (const float*)d_in[24]; const float* bd2b = (const float*)d_in[25];
    const float* wu0  = (const float*)d_in[26]; const float* bu0  = (const float*)d_in[27];
    const float* wu1  = (const float*)d_in[28]; const float* bu1  = (const float*)d_in[29];
    const float* wu2  = (const float*)d_in[30]; const float* bu2  = (const float*)d_in[31];
    const float* wfin = (const float*)d_in[32]; const float* bfin = (const float*)d_in[33];

    u16* ws = (u16*)d_ws;
    // region plan (bf16 elems, total 86,314,880 = 172.6 MB — proven)
    u16* s0in = ws + 0;          // 4 x 386x386 x 72 (dead after d0a)
    u16* x2   = ws + 0;          // halo'd, same geometry (u2 output; halo stays 0)
    u16* s1in = ws + 42913152;   // 4 x 194x194 x 128
    u16* scrB = ws + 42913152;   // 384-level scratch [2HW][64] = 18.87M <= 19.27M
    u16* s2in = ws + 62182784;   // 4 x 98x98 x 192
    u16* scr  = ws + 69558656;   // 192/96-level warp scratch (aliases t0/t1)
    u16* t0   = ws + 69558656;   // 4 x 194x194 x 32
    u16* t1   = ws + 74376064;   // 4 x 98x98 x 64
    u16* t2   = ws + 76834688;   // 4 x 50x50 x 96
    u16* s2b  = ws + 77794688;   // 4 x 48x48 x 96 (dense)
    u16* x0   = ws + 78679424;   // 4 x 96x96 x 64 (dense)
    u16* x1   = ws + 81038720;   // 4 x 192x192 x 32 (dense)
    u16* wtb  = ws + 85757312;
    u16* Wd0a = wtb;
    u16* Wd0b = Wd0a + 27648;
    u16* Wd1a = Wd0b + 9216;
    u16* Wd1b = Wd1a + 73728;
    u16* Wd2a = Wd1b + 36864;
    u16* Wd2b = Wd2a + 165888;
    u16* Wu0  = Wd2b + 82944;
    u16* Wu1  = Wu0 + 55296;
    u16* Wu2  = Wu1 + 36864;
    u16* Wfin = Wu2 + 46080;

    const int HW384 = 147456, HW192 = 36864, HW96 = 9216;

    // ---- 1) warp stage FIRST. 384-level: batch pairs, both frames staged
    //         interleaved in scrB, fused img+warp0+warp1 -> full 144B lines.
    for (int g = 0; g < 2; ++g) {
        int n0 = 2 * g;
        t_nhwc64<<<DIV_UP(2 * HW384, 256), 256, 0, stream>>>(
            c0_0 + (size_t)n0 * 32 * HW384, scrB, HW384, 2 * HW384, 0);
        t_nhwc64<<<DIV_UP(2 * HW384, 256), 256, 0, stream>>>(
            c1_0 + (size_t)n0 * 32 * HW384, scrB, HW384, 2 * HW384, 32);
        warp_full<<<DIV_UP(2 * HW384, 256), 256, 0, stream>>>(
            scrB,
            img0 + (size_t)n0 * 3 * HW384, img1 + (size_t)n0 * 3 * HW384,
            ft0 + (size_t)n0 * 2 * HW384, ft1 + (size_t)n0 * 2 * HW384,
            s0in + (size_t)n0 * 386 * 386 * 72, 2 * HW384);
    }
    for (int f = 0; f < 2; ++f) {
        t_nhwc<<<DIV_UP(4 * HW192, 256), 256, 0, stream>>>(
            f ? c1_1 : c0_1, scr, 48, HW192, 4 * HW192);
        warp_nhwc<<<DIV_UP(4 * HW192, 256), 256, 0, stream>>>(
            scr, f ? ft1s2 : ft0s2, s1in, f ? 80 : 32, 48, 192, 192, 128, 4 * HW192);
    }
    for (int f = 0; f < 2; ++f) {
        t_nhwc<<<DIV_UP(4 * HW96, 256), 256, 0, stream>>>(
            f ? c1_2 : c0_2, scr, 64, HW96, 4 * HW96);
        warp_nhwc<<<DIV_UP(4 * HW96, 256), 256, 0, stream>>>(
            scr, f ? ft1s4 : ft0s4, s2in, f ? 128 : 64, 64, 96, 96, 192, 4 * HW96);
    }

    // ---- 2) halo rings
    HZ6 hz = {{ {s0in, 384, 384, 72}, {s1in, 192, 192, 128}, {s2in, 96, 96, 192},
                {t0, 192, 192, 32},   {t1, 96, 96, 64},      {t2, 48, 48, 96} }};
    halo_zero<<<dim3(DIV_UP(4 * 386 * 386, 256), 6), 256, 0, stream>>>(hz);

    // ---- 3) weight transposes
    WT10 wt = {{ {wd0a, Wd0a, 32, 70, 32, 96, 1},  {wd0b, Wd0b, 32, 32, 32, 32, 0},
                 {wd1a, Wd1a, 64, 128, 64, 128, 0},{wd1b, Wd1b, 64, 64, 64, 64, 0},
                 {wd2a, Wd2a, 96, 192, 96, 192, 0},{wd2b, Wd2b, 96, 96, 96, 96, 0},
                 {wu0,  Wu0,  64, 96, 64, 96, 0},  {wu1,  Wu1,  32, 128, 32, 128, 0},
                 {wu2,  Wu2,  70, 64, 80, 64, 0},  {wfin, Wfin, 4, 70, 16, 96, 0} }};
    wtrans<<<dim3(DIV_UP(9 * 96 * 192, 256), 10), 256, 0, stream>>>(wt);

    // ---- down0
    conv_k<96,32,72, 32,32,32, 192,192,4,2,1, 0,0,32>
        <<<dim3(12*48,1,4),256,0,stream>>>(s0in,nullptr, 386L*386*72,0,0, 0,0,0,0, Wd0a,bd0a,t0);
    conv_k<32,32,32, 32,32,32, 192,192,8,1,1, 0,0,128>
        <<<dim3(12*24,1,4),256,0,stream>>>(t0,nullptr, 194L*194*32,0,0, 0,0,0,0, Wd0b,bd0b,s1in);

    // ---- down1
    conv_k<128,32,128, 64,64,64, 96,96,4,2,1, 0,0,64>
        <<<dim3(6*24,1,4),256,0,stream>>>(s1in,nullptr, 194L*194*128,0,0, 0,0,0,0, Wd1a,bd1a,t1);
    conv_k<64,64,64, 64,64,64, 96,96,4,1,1, 0,0,192>
        <<<dim3(6*24,1,4),256,0,stream>>>(t1,nullptr, 98L*98*64,0,0, 0,0,0,0, Wd1b,bd1b,s2in);

    // ---- down2
    conv_k<192,32,192, 96,96,96, 48,48,4,2,1, 0,0,96>
        <<<dim3(3*12,1,4),256,0,stream>>>(s2in,nullptr, 98L*98*192,0,0, 0,0,0,0, Wd2a,bd2a,t2);
    conv_k<96,32,96, 96,96,96, 48,48,4,1,1, 0,1,96>
        <<<dim3(3*12,1,4),256,0,stream>>>(t2,nullptr, 50L*50*96,0,0, 0,0,0,0, Wd2b,bd2b,s2b);

    // ---- decoder (fused up2x staging; round-15 verified)
    conv_k<96,32,96, 64,64,64, 96,96,4,1,1, 1,1,64>
        <<<dim3(6*24,1,4),256,0,stream>>>(s2b,s2b, 48L*48*96,48*96,96, 48L*48*96,48*96,96, 96,
                                          Wu0,bu0,x0);
    conv_k<128,64,128, 32,32,32, 192,192,8,1,1, 1,1,32>
        <<<dim3(12*24,1,4),256,0,stream>>>(x0, s2in + (size_t)(98+1)*192,
                                           96L*96*64,96*64,64, 98L*98*192,98*192,192, 64,
                                           Wu1,bu1,x1);
    conv_k<64,64,64, 80,70,70, 384,384,8,1,1, 1,0,72>
        <<<dim3(24*48,1,4),256,0,stream>>>(x1, s1in + (size_t)(194+1)*128,
                                           192L*192*32,192*32,32, 194L*194*128,194*128,128, 32,
                                           Wu2,bu2,x2);

    // ---- final conv (halo'd x2, GLD16 fast path + reg tail), HT=8, fp32 out
    conv_k<96,32,72, 16,4,4, 384,384,8,1,0, 0,2,0>
        <<<dim3(24*48,1,4),256,0,stream>>>(x2,nullptr, 386L*386*72,0,0, 0,0,0,0, Wfin,bfin,d_out);
}

// Round 19
// 704.412 us; speedup vs baseline: 1.1044x; 1.0001x over previous
//
#include <hip/hip_runtime.h>

#define DIV_UP(a,b) (((a)+(b)-1)/(b))

typedef unsigned short u16;
typedef __attribute__((ext_vector_type(8))) short s8v;
typedef __attribute__((ext_vector_type(4))) float f4v;
typedef __attribute__((ext_vector_type(2))) unsigned int u2v;

__device__ __forceinline__ float b2f(u16 x) {
    return __uint_as_float(((unsigned)x) << 16);
}
__device__ __forceinline__ u16 f2b(float f) {
    unsigned u = __float_as_uint(f);
    return (u16)((u + 0x7FFFu + ((u >> 16) & 1u)) >> 16);
}

#define GLD16(gp, lp) __builtin_amdgcn_global_load_lds( \
    (const __attribute__((address_space(1))) unsigned int*)(gp), \
    (__attribute__((address_space(3))) unsigned int*)(lp), 16, 0, 0)

// ===========================================================================
// combined halo zero: 6 halo'd NHWC buffers (runs AFTER warp stage — scr
// aliases t0/t1 and s1in, round-9 lesson)
// ===========================================================================
struct HZ { u16* p; int H, W, C; };
struct HZ6 { HZ d[6]; };
__global__ __launch_bounds__(256) void halo_zero(HZ6 Z)
{
    HZ d = Z.d[blockIdx.y];
    int pw = d.W + 2, ph = d.H + 2;
    int tot = 4 * ph * pw;
    int idx = blockIdx.x * 256 + threadIdx.x;
    if (idx >= tot) return;
    int r = idx % (ph * pw);
    int y = r / pw, x = r - y * pw;
    if (y > 0 && y <= d.H && x > 0 && x <= d.W) return;
    u16* p = d.p + (size_t)idx * d.C;
    s8v z = {0,0,0,0,0,0,0,0};
    for (int c = 0; c < d.C; c += 8) *(s8v*)(p + c) = z;
}

// ===========================================================================
// weight transpose: W[Cout][Cin][3][3] f32 -> W'[9][COUTP][CINP] bf16
// CINP MUST match conv's CINP (round-7 lesson). shift=1: s0in ch remap.
// ===========================================================================
struct WT { const float* src; u16* dst; int Cout, Cin, COUTP, CINP, shift; };
struct WT10 { WT d[10]; };
__global__ __launch_bounds__(256) void wtrans(WT10 Z)
{
    WT d = Z.d[blockIdx.y];
    int tot = 9 * d.COUTP * d.CINP;
    int idx = blockIdx.x * 256 + threadIdx.x;
    if (idx >= tot) return;
    int s = idx / (d.COUTP * d.CINP);
    int r = idx - s * (d.COUTP * d.CINP);
    int co = r / d.CINP, ci = r - co * d.CINP;
    int sci = ci;
    bool ok = (co < d.Cout);
    if (d.shift) {
        if (ci < 6)                 sci = ci;
        else if (ci >= 8 && ci < 72) sci = ci - 2;
        else                        ok = false;
    }
    ok = ok && (sci < d.Cin);
    float v = ok ? d.src[((size_t)co * d.Cin + sci) * 9 + s] : 0.f;
    d.dst[idx] = f2b(v);
}

// ===========================================================================
// NCHW fp32 frame (32ch, batch-pair base) -> interleaved NHWC bf16 [2HW][64]
// at channel offset cofs (frame0 -> 0, frame1 -> 32).
// ===========================================================================
__global__ __launch_bounds__(256) void t_nhwc64(
    const float* __restrict__ src, u16* __restrict__ dst,
    int HW, int total, int cofs)
{
    int idx = blockIdx.x * 256 + threadIdx.x;
    if (idx >= total) return;
    int n = idx / HW, p = idx - n * HW;
    const float* s = src + (size_t)n * 32 * HW + p;
    u16* d = dst + (size_t)idx * 64 + cofs;
#pragma unroll
    for (int c8 = 0; c8 < 32; c8 += 8) {
        s8v v;
#pragma unroll
        for (int i = 0; i < 8; ++i)
            v[i] = (short)f2b(s[(size_t)(c8 + i) * HW]);
        *(s8v*)(d + c8) = v;
    }
}

// ===========================================================================
// fused 384-level glue: img channels + BOTH frame warps per pixel, one
// contiguous 144B store (write-combined; replaces img_cat + 2x warp_nhwc).
// fr2: [2HW][64] (frame0 ch0-31, frame1 ch32-63). All float ptrs batch-pair
// offset. dst: s0in + n0*386*386*72.
// ===========================================================================
__global__ __launch_bounds__(256) void warp_full(
    const u16* __restrict__ fr2,
    const float* __restrict__ i0, const float* __restrict__ i1,
    const float* __restrict__ fl0, const float* __restrict__ fl1,
    u16* __restrict__ dst, int total)
{
    const int HW = 147456, W = 384, H = 384;
    int idx = blockIdx.x * 256 + threadIdx.x;
    if (idx >= total) return;
    int n = idx / HW, r = idx - n * HW;
    int i = r / W, j = r - i * W;

    s8v ov[9];
#pragma unroll
    for (int c = 0; c < 3; ++c) {
        ov[0][c]     = (short)f2b(i0[((size_t)(n * 3 + c)) * HW + r]);
        ov[0][3 + c] = (short)f2b(i1[((size_t)(n * 3 + c)) * HW + r]);
    }
    ov[0][6] = 0; ov[0][7] = 0;

#pragma unroll
    for (int f = 0; f < 2; ++f) {
        const float* flow = f ? fl1 : fl0;
        float fx = flow[((size_t)(n * 2 + 0)) * HW + r];
        float fy = flow[((size_t)(n * 2 + 1)) * HW + r];
        float x = (float)j + fx * ((float)W / (float)(W - 1));
        float y = (float)i + fy * ((float)H / (float)(H - 1));
        x = fminf(fmaxf(x, 0.f), (float)(W - 1));
        y = fminf(fmaxf(y, 0.f), (float)(H - 1));
        float x0f = floorf(x), y0f = floorf(y);
        int ix0 = (int)x0f, iy0 = (int)y0f;
        int ix1 = ix0 + 1; if (ix1 > W - 1) ix1 = W - 1;
        int iy1 = iy0 + 1; if (iy1 > H - 1) iy1 = H - 1;
        float wx = x - x0f, wy = y - y0f;
        float w00 = (1.f - wx) * (1.f - wy), w01 = wx * (1.f - wy);
        float w10 = (1.f - wx) * wy,         w11 = wx * wy;

        const u16* fb  = fr2 + (size_t)n * HW * 64 + 32 * f;
        const u16* p00 = fb + (size_t)(iy0 * W + ix0) * 64;
        const u16* p01 = fb + (size_t)(iy0 * W + ix1) * 64;
        const u16* p10 = fb + (size_t)(iy1 * W + ix0) * 64;
        const u16* p11 = fb + (size_t)(iy1 * W + ix1) * 64;

#pragma unroll
        for (int c8 = 0; c8 < 32; c8 += 8) {
            s8v a = *(const s8v*)(p00 + c8);
            s8v b = *(const s8v*)(p01 + c8);
            s8v c = *(const s8v*)(p10 + c8);
            s8v d = *(const s8v*)(p11 + c8);
#pragma unroll
            for (int t = 0; t < 8; ++t) {
                int ch = 8 + 32 * f + c8 + t;
                ov[ch >> 3][ch & 7] =
                    (short)f2b(w00 * b2f((u16)a[t]) + w01 * b2f((u16)b[t])
                             + w10 * b2f((u16)c[t]) + w11 * b2f((u16)d[t]));
            }
        }
    }

    u16* db = dst + ((size_t)n * 386 * 386 + (size_t)(i + 1) * 386 + (j + 1)) * 72;
#pragma unroll
    for (int k = 0; k < 9; ++k) *(s8v*)(db + 8 * k) = ov[k];
}

// ===========================================================================
// NCHW fp32 frame -> dense NHWC bf16 [total][C]  (192/96 levels)
// ===========================================================================
__global__ __launch_bounds__(256) void t_nhwc(
    const float* __restrict__ src, u16* __restrict__ dst, int C, int HW, int total)
{
    int idx = blockIdx.x * 256 + threadIdx.x;
    if (idx >= total) return;
    int n = idx / HW, p = idx - n * HW;
    const float* s = src + (size_t)n * C * HW + p;
    u16* d = dst + (size_t)idx * C;
    for (int c8 = 0; c8 < C; c8 += 8) {
        s8v v;
#pragma unroll
        for (int i = 0; i < 8; ++i)
            v[i] = (short)f2b(s[(size_t)(c8 + i) * HW]);
        *(s8v*)(d + c8) = v;
    }
}

// ===========================================================================
// backward_warp from dense NHWC bf16 frame -> halo'd NHWC dst slot (192/96)
// ===========================================================================
__global__ __launch_bounds__(256) void warp_nhwc(
    const u16* __restrict__ fr, const float* __restrict__ flow,
    u16* __restrict__ dst, int chb, int C, int H, int W, int CALLOC, int total)
{
    int HW = H * W;
    int idx = blockIdx.x * 256 + threadIdx.x;
    if (idx >= total) return;
    int n = idx / HW, r = idx - n * HW;
    int i = r / W, j = r - i * W;

    float fx = flow[((size_t)n * 2 + 0) * HW + r];
    float fy = flow[((size_t)n * 2 + 1) * HW + r];
    float x = (float)j + fx * ((float)W / (float)(W - 1));
    float y = (float)i + fy * ((float)H / (float)(H - 1));
    x = fminf(fmaxf(x, 0.f), (float)(W - 1));
    y = fminf(fmaxf(y, 0.f), (float)(H - 1));
    float x0f = floorf(x), y0f = floorf(y);
    int ix0 = (int)x0f, iy0 = (int)y0f;
    int ix1 = ix0 + 1; if (ix1 > W - 1) ix1 = W - 1;
    int iy1 = iy0 + 1; if (iy1 > H - 1) iy1 = H - 1;
    float wx = x - x0f, wy = y - y0f;
    float w00 = (1.f - wx) * (1.f - wy), w01 = wx * (1.f - wy);
    float w10 = (1.f - wx) * wy,         w11 = wx * wy;

    const u16* fb  = fr + (size_t)n * HW * C;
    const u16* p00 = fb + (size_t)(iy0 * W + ix0) * C;
    const u16* p01 = fb + (size_t)(iy0 * W + ix1) * C;
    const u16* p10 = fb + (size_t)(iy1 * W + ix0) * C;
    const u16* p11 = fb + (size_t)(iy1 * W + ix1) * C;
    u16* db = dst + ((size_t)n * (H + 2) * (W + 2) + (size_t)(i + 1) * (W + 2) + (j + 1)) * CALLOC + chb;

    for (int c8 = 0; c8 < C; c8 += 8) {
        s8v a = *(const s8v*)(p00 + c8);
        s8v b = *(const s8v*)(p01 + c8);
        s8v c = *(const s8v*)(p10 + c8);
        s8v d = *(const s8v*)(p11 + c8);
        s8v o;
#pragma unroll
        for (int t = 0; t < 8; ++t)
            o[t] = (short)f2b(w00 * b2f((u16)a[t]) + w01 * b2f((u16)b[t])
                            + w10 * b2f((u16)c[t]) + w11 * b2f((u16)d[t]));
        *(s8v*)(db + c8) = o;
    }
}

// ===========================================================================
// MFMA implicit-GEMM 3x3 conv — round-15/17 verified structure (GLD16 input
// staging + double-buffered weight LDS; integer-parity bilinear SRC_MODE=1).
//  SRC_MODE 0: halo'd NHWC
//  SRC_MODE 1: fused 2x-bilinear-upsample of virtual concat [A | B]
//  OUT_MODE 0: halo'd NHWC, 1: dense NHWC, 2: NCHW fp32
// ===========================================================================
template<int CINP, int CHUNK, int CIN_ALLOC, int COUTP, int COUT, int STORE_LIM,
         int HO, int WO, int HT, int STRIDE, int RELU, int SRC_MODE, int OUT_MODE, int OCALLOC>
__global__ __launch_bounds__(256) void conv_k(
    const u16* __restrict__ srcA, const u16* __restrict__ srcB,
    long nsA, int rsA, int cA, long nsB, int rsB, int cB, int splitC,
    const u16* __restrict__ wt, const float* __restrict__ bias,
    void* __restrict__ outv)
{
    constexpr int WROWS = HT / 4;
    constexpr int ROWS  = (STRIDE == 1) ? HT + 2 : 2 * HT + 1;
    constexpr int COLS  = (STRIDE == 1) ? 18 : 33;
    constexpr int SUBS  = CHUNK / 8;
    constexpr int LSUB  = (SUBS == 8) ? 3 : 2;
    constexpr int XM    = SUBS - 1;
    constexpr int CH2   = CHUNK * 2;
    constexpr int NCHK  = CINP / CHUNK;
    constexpr int KK    = CHUNK / 32;
    constexpr int MT    = COUTP / 16;
    constexpr int NPX   = ROWS * COLS;
    constexpr int IN_B  = NPX * CH2;
    constexpr int W_B   = COUTP * CH2;
    constexpr int WI    = WO * STRIDE;
    constexpr int Hs    = HO / 2, Ws = WO / 2;
    constexpr long NSO  = (OUT_MODE == 0) ? (long)(HO + 2) * (WO + 2) * OCALLOC
                                          : (long)HO * WO * OCALLOC;

    __shared__ s8v ldsv[(IN_B + 2 * W_B) / 16];
    char* lds  = (char*)ldsv;
    char* ldw0 = lds + IN_B;
    char* ldw1 = ldw0 + W_B;

    const int tid  = threadIdx.x;
    const int wv   = tid >> 6;
    const int lane = tid & 63;
    const int lr   = lane & 15;
    const int koct = lane >> 4;
    const int bx   = blockIdx.x, n = blockIdx.z;
    const int tx   = (bx % (WO / 16)) * 16;
    const int ty   = (bx / (WO / 16)) * HT;

    f4v acc[MT][WROWS];
#pragma unroll
    for (int m = 0; m < MT; ++m)
#pragma unroll
        for (int r = 0; r < WROWS; ++r) acc[m][r] = (f4v){0.f, 0.f, 0.f, 0.f};

    float bv[MT][4];
#pragma unroll
    for (int m = 0; m < MT; ++m)
#pragma unroll
        for (int j = 0; j < 4; ++j) {
            int co = m * 16 + koct * 4 + j;
            bv[m][j] = (co < COUT) ? bias[co] : 0.f;
        }

    for (int cig = 0; cig < NCHK; ++cig) {
        if (cig) __syncthreads();

        // ---------------- stage input chunk ----------------
        if constexpr (SRC_MODE == 0) {
            const u16* ns = srcA + (size_t)n * nsA;
            if (CIN_ALLOC >= CINP || (cig + 1) * CHUNK <= CIN_ALLOC) {
                for (int t = tid; t < NPX * SUBS; t += 256) {
                    int q = t >> LSUB, sub = t & XM;
                    int iy = q / COLS, ix = q - iy * COLS;
                    int xr = (STRIDE == 1) ? (q & XM) : ((q >> 1) & XM);
                    int ci0 = cig * CHUNK + (sub ^ xr) * 8;
                    const u16* g = ns + ((size_t)(ty * STRIDE + iy) * (WI + 2)
                                         + (tx * STRIDE + ix)) * CIN_ALLOC + ci0;
                    GLD16(g, lds + t * 16);
                }
            } else {
                for (int t = tid; t < NPX * SUBS; t += 256) {
                    int q = t >> LSUB, sub = t & XM;
                    int iy = q / COLS, ix = q - iy * COLS;
                    int xr = (STRIDE == 1) ? (q & XM) : ((q >> 1) & XM);
                    int ci0 = cig * CHUNK + (sub ^ xr) * 8;
                    s8v v = {0,0,0,0,0,0,0,0};
                    if (ci0 < CIN_ALLOC)
                        v = *(const s8v*)(ns + ((size_t)(ty * STRIDE + iy) * (WI + 2)
                                                + (tx * STRIDE + ix)) * CIN_ALLOC + ci0);
                    *(s8v*)(lds + t * 16) = v;
                }
            }
        } else {   // SRC_MODE == 1: fused up2x of [A | B], integer bilinear
            for (int t = tid; t < NPX * SUBS; t += 256) {
                int q = t >> LSUB, sub = t & XM;
                int iy = q / COLS, ix = q - iy * COLS;
                int ssub = sub ^ (q & XM);
                int ci0 = cig * CHUNK + ssub * 8;
                int gy = ty + iy - 1, gx = tx + ix - 1;
                s8v val = {0,0,0,0,0,0,0,0};
                if ((unsigned)gy < (unsigned)HO && (unsigned)gx < (unsigned)WO) {
                    const u16* sp; int rs, cal, cof; long nss;
                    if (ci0 < splitC) { sp = srcA; nss = nsA; rs = rsA; cal = cA; cof = ci0; }
                    else              { sp = srcB; nss = nsB; rs = rsB; cal = cB; cof = ci0 - splitC; }
                    sp += (size_t)n * nss;
                    int y0 = (gy >> 1) + (gy & 1) - 1;
                    int x0 = (gx >> 1) + (gx & 1) - 1;
                    float wy = (gy & 1) ? 0.25f : 0.75f;
                    float wx = (gx & 1) ? 0.25f : 0.75f;
                    int y1 = min(y0 + 1, Hs - 1); y0 = max(y0, 0);
                    int x1 = min(x0 + 1, Ws - 1); x0 = max(x0, 0);
                    const s8v a = *(const s8v*)(sp + (size_t)y0 * rs + (size_t)x0 * cal + cof);
                    const s8v b = *(const s8v*)(sp + (size_t)y0 * rs + (size_t)x1 * cal + cof);
                    const s8v c = *(const s8v*)(sp + (size_t)y1 * rs + (size_t)x0 * cal + cof);
                    const s8v d = *(const s8v*)(sp + (size_t)y1 * rs + (size_t)x1 * cal + cof);
                    float w00 = (1.f - wx) * (1.f - wy), w01 = wx * (1.f - wy);
                    float w10 = (1.f - wx) * wy,         w11 = wx * wy;
#pragma unroll
                    for (int i = 0; i < 8; ++i) {
                        float v = w00 * b2f((u16)a[i]) + w01 * b2f((u16)b[i])
                                + w10 * b2f((u16)c[i]) + w11 * b2f((u16)d[i]);
                        val[i] = (short)f2b(v);
                    }
                }
                *(s8v*)(lds + t * 16) = val;
            }
        }

        // ---------------- weight slice staging (double-buffered LDS) ------
        auto stageW = [&](int s, char* dstb) {
            for (int t = tid; t < COUTP * SUBS; t += 256) {
                int co = t >> LSUB, sub = t & XM;
                int ssub = sub ^ (co & XM);
                const u16* g = wt + ((size_t)(s * COUTP + co) * CINP + cig * CHUNK + ssub * 8);
                GLD16(g, dstb + t * 16);
            }
        };
        stageW(0, ldw0);

#pragma unroll
        for (int s = 0; s < 9; ++s) {
            __syncthreads();
            if (s < 8) stageW(s + 1, (s & 1) ? ldw0 : ldw1);
            char* wc = (s & 1) ? ldw1 : ldw0;
            const int dy = s / 3, dx = s - dy * 3;
#pragma unroll
            for (int kk = 0; kk < KK; ++kk) {
                const int koff = kk * 64 + koct * 16;
                s8v bfr[WROWS];
#pragma unroll
                for (int r = 0; r < WROWS; ++r) {
                    int orow = wv * WROWS + r;
                    int q, xr;
                    if (STRIDE == 1) { q = (orow + dy) * COLS + lr + dx; xr = q & XM; }
                    else             { q = (2 * orow + dy) * COLS + 2 * lr + dx; xr = (q >> 1) & XM; }
                    bfr[r] = *(const s8v*)(lds + q * CH2 + (koff ^ (xr << 4)));
                }
#pragma unroll
                for (int m = 0; m < MT; ++m) {
                    s8v afr = *(const s8v*)(wc + (m * 16 + lr) * CH2 + (koff ^ ((lr & XM) << 4)));
#pragma unroll
                    for (int r = 0; r < WROWS; ++r)
                        acc[m][r] = __builtin_amdgcn_mfma_f32_16x16x32_bf16(afr, bfr[r], acc[m][r], 0, 0, 0);
                }
            }
        }
    }

    // ---------------- epilogue ----------------
#pragma unroll
    for (int m = 0; m < MT; ++m) {
#pragma unroll
        for (int r = 0; r < WROWS; ++r) {
            int row = ty + wv * WROWS + r, col = tx + lr;
            float x0 = acc[m][r][0] + bv[m][0];
            float x1 = acc[m][r][1] + bv[m][1];
            float x2 = acc[m][r][2] + bv[m][2];
            float x3 = acc[m][r][3] + bv[m][3];
            if (RELU) {
                x0 = fmaxf(x0, 0.f); x1 = fmaxf(x1, 0.f);
                x2 = fmaxf(x2, 0.f); x3 = fmaxf(x3, 0.f);
            }
            int co0 = m * 16 + koct * 4;
            if constexpr (OUT_MODE == 2) {
                float* op = (float*)outv;
                float xs[4] = {x0, x1, x2, x3};
#pragma unroll
                for (int j = 0; j < 4; ++j)
                    if (co0 + j < STORE_LIM)
                        op[((size_t)(n * 4 + co0 + j) * HO + row) * WO + col] = xs[j];
            } else {
                size_t pix = (OUT_MODE == 0)
                    ? ((size_t)(row + 1) * (WO + 2) + (col + 1))
                    : ((size_t)row * WO + col);
                u16* ob = (u16*)outv + (size_t)n * NSO + pix * OCALLOC + co0;
                if (co0 + 3 < STORE_LIM) {
                    unsigned lo = (unsigned)f2b(x0) | ((unsigned)f2b(x1) << 16);
                    unsigned hi = (unsigned)f2b(x2) | ((unsigned)f2b(x3) << 16);
                    *(u2v*)ob = (u2v){lo, hi};
                } else {
                    float xs[4] = {x0, x1, x2, x3};
#pragma unroll
                    for (int j = 0; j < 4; ++j)
                        if (co0 + j < STORE_LIM) ob[j] = f2b(xs[j]);
                }
            }
        }
    }
}

// ===========================================================================
extern "C" void kernel_launch(void* const* d_in, const int* in_sizes, int n_in,
                              void* d_out, int out_size, void* d_ws, size_t ws_size,
                              hipStream_t stream)
{
    const float* img0  = (const float*)d_in[0];
    const float* img1  = (const float*)d_in[1];
    const float* ft0   = (const float*)d_in[2];
    const float* ft1   = (const float*)d_in[3];
    const float* ft0s2 = (const float*)d_in[4];
    const float* ft1s2 = (const float*)d_in[5];
    const float* ft0s4 = (const float*)d_in[6];
    const float* ft1s4 = (const float*)d_in[7];
    const float* c0_0  = (const float*)d_in[8];
    const float* c0_1  = (const float*)d_in[9];
    const float* c0_2  = (const float*)d_in[10];
    const float* c1_0  = (const float*)d_in[11];
    const float* c1_1  = (const float*)d_in[12];
    const float* c1_2  = (const float*)d_in[13];
    const float* wd0a = (const float*)d_in[14]; const float* bd0a = (const float*)d_in[15];
    const float* wd0b = (const float*)d_in[16]; const float* bd0b = (const float*)d_in[17];
    const float* wd1a = (const float*)d_in[18]; const float* bd1a = (const float*)d_in[19];
    const float* wd1b = (const float*)d_in[20]; const float* bd1b = (const float*)d_in[21];
    const float* wd2a = (const float*)d_in[22]; const float* bd2a = (const float*)d_in[23];
    const float* wd2b = (const float*)d_in[24]; const float* bd2b = (const float*)d_in[25];
    const float* wu0  = (const float*)d_in[26]; const float* bu0  = (const float*)d_in[27];
    const float* wu1  = (const float*)d_in[28]; const float* bu1  = (const float*)d_in[29];
    const float* wu2  = (const float*)d_in[30]; const float* bu2  = (const float*)d_in[31];
    const float* wfin = (const float*)d_in[32]; const float* bfin = (const float*)d_in[33];

    u16* ws = (u16*)d_ws;
    // region plan (bf16 elems, total 86,314,880 = 172.6 MB — proven)
    u16* s0in = ws + 0;          // 4 x 386x386 x 72 (dead after d0a)
    u16* x2   = ws + 0;          // halo'd, same geometry (u2 output; halo stays 0)
    u16* s1in = ws + 42913152;   // 4 x 194x194 x 128
    u16* scrB = ws + 42913152;   // 384-level scratch [2HW][64] (dead before d0b)
    u16* s2in = ws + 62182784;   // 4 x 98x98 x 192
    u16* scr  = ws + 69558656;   // 192/96-level warp scratch (aliases t0/t1)
    u16* t0   = ws + 69558656;   // 4 x 194x194 x 32
    u16* t1   = ws + 74376064;   // 4 x 98x98 x 64
    u16* t2   = ws + 76834688;   // 4 x 50x50 x 96
    u16* s2b  = ws + 77794688;   // 4 x 48x48 x 96 (dense)
    u16* x0   = ws + 78679424;   // 4 x 96x96 x 64 (dense)
    u16* x1   = ws + 81038720;   // 4 x 192x192 x 32 (dense)
    u16* wtb  = ws + 85757312;
    u16* Wd0a = wtb;
    u16* Wd0b = Wd0a + 27648;
    u16* Wd1a = Wd0b + 9216;
    u16* Wd1b = Wd1a + 73728;
    u16* Wd2a = Wd1b + 36864;
    u16* Wd2b = Wd2a + 165888;
    u16* Wu0  = Wd2b + 82944;
    u16* Wu1  = Wu0 + 55296;
    u16* Wu2  = Wu1 + 36864;
    u16* Wfin = Wu2 + 46080;

    const int HW384 = 147456, HW192 = 36864, HW96 = 9216;

    // ---- 1) warp stage FIRST. 384-level: batch pairs, both frames staged
    //         interleaved in scrB, fused img+warp0+warp1 -> full 144B lines.
    for (int g = 0; g < 2; ++g) {
        int n0 = 2 * g;
        t_nhwc64<<<DIV_UP(2 * HW384, 256), 256, 0, stream>>>(
            c0_0 + (size_t)n0 * 32 * HW384, scrB, HW384, 2 * HW384, 0);
        t_nhwc64<<<DIV_UP(2 * HW384, 256), 256, 0, stream>>>(
            c1_0 + (size_t)n0 * 32 * HW384, scrB, HW384, 2 * HW384, 32);
        warp_full<<<DIV_UP(2 * HW384, 256), 256, 0, stream>>>(
            scrB,
            img0 + (size_t)n0 * 3 * HW384, img1 + (size_t)n0 * 3 * HW384,
            ft0 + (size_t)n0 * 2 * HW384, ft1 + (size_t)n0 * 2 * HW384,
            s0in + (size_t)n0 * 386 * 386 * 72, 2 * HW384);
    }
    for (int f = 0; f < 2; ++f) {
        t_nhwc<<<DIV_UP(4 * HW192, 256), 256, 0, stream>>>(
            f ? c1_1 : c0_1, scr, 48, HW192, 4 * HW192);
        warp_nhwc<<<DIV_UP(4 * HW192, 256), 256, 0, stream>>>(
            scr, f ? ft1s2 : ft0s2, s1in, f ? 80 : 32, 48, 192, 192, 128, 4 * HW192);
    }
    for (int f = 0; f < 2; ++f) {
        t_nhwc<<<DIV_UP(4 * HW96, 256), 256, 0, stream>>>(
            f ? c1_2 : c0_2, scr, 64, HW96, 4 * HW96);
        warp_nhwc<<<DIV_UP(4 * HW96, 256), 256, 0, stream>>>(
            scr, f ? ft1s4 : ft0s4, s2in, f ? 128 : 64, 64, 96, 96, 192, 4 * HW96);
    }

    // ---- 2) halo rings
    HZ6 hz = {{ {s0in, 384, 384, 72}, {s1in, 192, 192, 128}, {s2in, 96, 96, 192},
                {t0, 192, 192, 32},   {t1, 96, 96, 64},      {t2, 48, 48, 96} }};
    halo_zero<<<dim3(DIV_UP(4 * 386 * 386, 256), 6), 256, 0, stream>>>(hz);

    // ---- 3) weight transposes
    WT10 wt = {{ {wd0a, Wd0a, 32, 70, 32, 96, 1},  {wd0b, Wd0b, 32, 32, 32, 32, 0},
                 {wd1a, Wd1a, 64, 128, 64, 128, 0},{wd1b, Wd1b, 64, 64, 64, 64, 0},
                 {wd2a, Wd2a, 96, 192, 96, 192, 0},{wd2b, Wd2b, 96, 96, 96, 96, 0},
                 {wu0,  Wu0,  64, 96, 64, 96, 0},  {wu1,  Wu1,  32, 128, 32, 128, 0},
                 {wu2,  Wu2,  70, 64, 80, 64, 0},  {wfin, Wfin, 4, 70, 16, 96, 0} }};
    wtrans<<<dim3(DIV_UP(9 * 96 * 192, 256), 10), 256, 0, stream>>>(wt);

    // ---- down0
    conv_k<96,32,72, 32,32,32, 192,192,4,2,1, 0,0,32>
        <<<dim3(12*48,1,4),256,0,stream>>>(s0in,nullptr, 386L*386*72,0,0, 0,0,0,0, Wd0a,bd0a,t0);
    conv_k<32,32,32, 32,32,32, 192,192,8,1,1, 0,0,128>
        <<<dim3(12*24,1,4),256,0,stream>>>(t0,nullptr, 194L*194*32,0,0, 0,0,0,0, Wd0b,bd0b,s1in);

    // ---- down1
    conv_k<128,32,128, 64,64,64, 96,96,4,2,1, 0,0,64>
        <<<dim3(6*24,1,4),256,0,stream>>>(s1in,nullptr, 194L*194*128,0,0, 0,0,0,0, Wd1a,bd1a,t1);
    conv_k<64,64,64, 64,64,64, 96,96,4,1,1, 0,0,192>
        <<<dim3(6*24,1,4),256,0,stream>>>(t1,nullptr, 98L*98*64,0,0, 0,0,0,0, Wd1b,bd1b,s2in);

    // ---- down2
    conv_k<192,32,192, 96,96,96, 48,48,4,2,1, 0,0,96>
        <<<dim3(3*12,1,4),256,0,stream>>>(s2in,nullptr, 98L*98*192,0,0, 0,0,0,0, Wd2a,bd2a,t2);
    conv_k<96,32,96, 96,96,96, 48,48,4,1,1, 0,1,96>
        <<<dim3(3*12,1,4),256,0,stream>>>(t2,nullptr, 50L*50*96,0,0, 0,0,0,0, Wd2b,bd2b,s2b);

    // ---- decoder (fused up2x staging; round-15/17 verified)
    conv_k<96,32,96, 64,64,64, 96,96,4,1,1, 1,1,64>
        <<<dim3(6*24,1,4),256,0,stream>>>(s2b,s2b, 48L*48*96,48*96,96, 48L*48*96,48*96,96, 96,
                                          Wu0,bu0,x0);
    conv_k<128,64,128, 32,32,32, 192,192,8,1,1, 1,1,32>
        <<<dim3(12*24,1,4),256,0,stream>>>(x0, s2in + (size_t)(98+1)*192,
                                           96L*96*64,96*64,64, 98L*98*192,98*192,192, 64,
                                           Wu1,bu1,x1);
    conv_k<64,64,64, 80,70,70, 384,384,8,1,1, 1,0,72>
        <<<dim3(24*48,1,4),256,0,stream>>>(x1, s1in + (size_t)(194+1)*128,
                                           192L*192*32,192*32,32, 194L*194*128,194*128,128, 32,
                                           Wu2,bu2,x2);

    // ---- final conv (halo'd x2, GLD16 fast path + reg tail), HT=8, fp32 out
    conv_k<96,32,72, 16,4,4, 384,384,8,1,0, 0,2,0>
        <<<dim3(24*48,1,4),256,0,stream>>>(x2,nullptr, 386L*386*72,0,0, 0,0,0,0, Wfin,bfin,d_out);
}

// Round 20
// 698.803 us; speedup vs baseline: 1.1133x; 1.0080x over previous
//
#include <hip/hip_runtime.h>

#define DIV_UP(a,b) (((a)+(b)-1)/(b))

typedef unsigned short u16;
typedef __attribute__((ext_vector_type(8))) short s8v;
typedef __attribute__((ext_vector_type(4))) float f4v;
typedef __attribute__((ext_vector_type(2))) unsigned int u2v;

__device__ __forceinline__ float b2f(u16 x) {
    return __uint_as_float(((unsigned)x) << 16);
}
__device__ __forceinline__ u16 f2b(float f) {
    unsigned u = __float_as_uint(f);
    return (u16)((u + 0x7FFFu + ((u >> 16) & 1u)) >> 16);
}

#define GLD16(gp, lp) __builtin_amdgcn_global_load_lds( \
    (const __attribute__((address_space(1))) unsigned int*)(gp), \
    (__attribute__((address_space(3))) unsigned int*)(lp), 16, 0, 0)

// ===========================================================================
// combined halo zero: 6 halo'd NHWC buffers (runs AFTER warp stage — scr
// aliases t0/t1 and s1in, round-9 lesson)
// ===========================================================================
struct HZ { u16* p; int H, W, C; };
struct HZ6 { HZ d[6]; };
__global__ __launch_bounds__(256) void halo_zero(HZ6 Z)
{
    HZ d = Z.d[blockIdx.y];
    int pw = d.W + 2, ph = d.H + 2;
    int tot = 4 * ph * pw;
    int idx = blockIdx.x * 256 + threadIdx.x;
    if (idx >= tot) return;
    int r = idx % (ph * pw);
    int y = r / pw, x = r - y * pw;
    if (y > 0 && y <= d.H && x > 0 && x <= d.W) return;
    u16* p = d.p + (size_t)idx * d.C;
    s8v z = {0,0,0,0,0,0,0,0};
    for (int c = 0; c < d.C; c += 8) *(s8v*)(p + c) = z;
}

// ===========================================================================
// weight transpose: W[Cout][Cin][3][3] f32 -> W'[9][COUTP][CINP] bf16
// CINP MUST match conv's CINP (round-7 lesson). shift=1: s0in ch remap.
// ===========================================================================
struct WT { const float* src; u16* dst; int Cout, Cin, COUTP, CINP, shift; };
struct WT10 { WT d[10]; };
__global__ __launch_bounds__(256) void wtrans(WT10 Z)
{
    WT d = Z.d[blockIdx.y];
    int tot = 9 * d.COUTP * d.CINP;
    int idx = blockIdx.x * 256 + threadIdx.x;
    if (idx >= tot) return;
    int s = idx / (d.COUTP * d.CINP);
    int r = idx - s * (d.COUTP * d.CINP);
    int co = r / d.CINP, ci = r - co * d.CINP;
    int sci = ci;
    bool ok = (co < d.Cout);
    if (d.shift) {
        if (ci < 6)                 sci = ci;
        else if (ci >= 8 && ci < 72) sci = ci - 2;
        else                        ok = false;
    }
    ok = ok && (sci < d.Cin);
    float v = ok ? d.src[((size_t)co * d.Cin + sci) * 9 + s] : 0.f;
    d.dst[idx] = f2b(v);
}

// ===========================================================================
// NCHW fp32 frame (32ch, batch-pair base) -> interleaved NHWC bf16 [2HW][64]
// at channel offset cofs (frame0 -> 0, frame1 -> 32).
// ===========================================================================
__global__ __launch_bounds__(256) void t_nhwc64(
    const float* __restrict__ src, u16* __restrict__ dst,
    int HW, int total, int cofs)
{
    int idx = blockIdx.x * 256 + threadIdx.x;
    if (idx >= total) return;
    int n = idx / HW, p = idx - n * HW;
    const float* s = src + (size_t)n * 32 * HW + p;
    u16* d = dst + (size_t)idx * 64 + cofs;
#pragma unroll
    for (int c8 = 0; c8 < 32; c8 += 8) {
        s8v v;
#pragma unroll
        for (int i = 0; i < 8; ++i)
            v[i] = (short)f2b(s[(size_t)(c8 + i) * HW]);
        *(s8v*)(d + c8) = v;
    }
}

// ===========================================================================
// fused 384-level glue: img channels + BOTH frame warps per pixel, one
// contiguous 144B store (write-combined; replaces img_cat + 2x warp_nhwc).
// ===========================================================================
__global__ __launch_bounds__(256) void warp_full(
    const u16* __restrict__ fr2,
    const float* __restrict__ i0, const float* __restrict__ i1,
    const float* __restrict__ fl0, const float* __restrict__ fl1,
    u16* __restrict__ dst, int total)
{
    const int HW = 147456, W = 384, H = 384;
    int idx = blockIdx.x * 256 + threadIdx.x;
    if (idx >= total) return;
    int n = idx / HW, r = idx - n * HW;
    int i = r / W, j = r - i * W;

    s8v ov[9];
#pragma unroll
    for (int c = 0; c < 3; ++c) {
        ov[0][c]     = (short)f2b(i0[((size_t)(n * 3 + c)) * HW + r]);
        ov[0][3 + c] = (short)f2b(i1[((size_t)(n * 3 + c)) * HW + r]);
    }
    ov[0][6] = 0; ov[0][7] = 0;

#pragma unroll
    for (int f = 0; f < 2; ++f) {
        const float* flow = f ? fl1 : fl0;
        float fx = flow[((size_t)(n * 2 + 0)) * HW + r];
        float fy = flow[((size_t)(n * 2 + 1)) * HW + r];
        float x = (float)j + fx * ((float)W / (float)(W - 1));
        float y = (float)i + fy * ((float)H / (float)(H - 1));
        x = fminf(fmaxf(x, 0.f), (float)(W - 1));
        y = fminf(fmaxf(y, 0.f), (float)(H - 1));
        float x0f = floorf(x), y0f = floorf(y);
        int ix0 = (int)x0f, iy0 = (int)y0f;
        int ix1 = ix0 + 1; if (ix1 > W - 1) ix1 = W - 1;
        int iy1 = iy0 + 1; if (iy1 > H - 1) iy1 = H - 1;
        float wx = x - x0f, wy = y - y0f;
        float w00 = (1.f - wx) * (1.f - wy), w01 = wx * (1.f - wy);
        float w10 = (1.f - wx) * wy,         w11 = wx * wy;

        const u16* fb  = fr2 + (size_t)n * HW * 64 + 32 * f;
        const u16* p00 = fb + (size_t)(iy0 * W + ix0) * 64;
        const u16* p01 = fb + (size_t)(iy0 * W + ix1) * 64;
        const u16* p10 = fb + (size_t)(iy1 * W + ix0) * 64;
        const u16* p11 = fb + (size_t)(iy1 * W + ix1) * 64;

#pragma unroll
        for (int c8 = 0; c8 < 32; c8 += 8) {
            s8v a = *(const s8v*)(p00 + c8);
            s8v b = *(const s8v*)(p01 + c8);
            s8v c = *(const s8v*)(p10 + c8);
            s8v d = *(const s8v*)(p11 + c8);
#pragma unroll
            for (int t = 0; t < 8; ++t) {
                int ch = 8 + 32 * f + c8 + t;
                ov[ch >> 3][ch & 7] =
                    (short)f2b(w00 * b2f((u16)a[t]) + w01 * b2f((u16)b[t])
                             + w10 * b2f((u16)c[t]) + w11 * b2f((u16)d[t]));
            }
        }
    }

    u16* db = dst + ((size_t)n * 386 * 386 + (size_t)(i + 1) * 386 + (j + 1)) * 72;
#pragma unroll
    for (int k = 0; k < 9; ++k) *(s8v*)(db + 8 * k) = ov[k];
}

// ===========================================================================
// NCHW fp32 frame -> dense NHWC bf16 [total][C]  (192/96 levels)
// ===========================================================================
__global__ __launch_bounds__(256) void t_nhwc(
    const float* __restrict__ src, u16* __restrict__ dst, int C, int HW, int total)
{
    int idx = blockIdx.x * 256 + threadIdx.x;
    if (idx >= total) return;
    int n = idx / HW, p = idx - n * HW;
    const float* s = src + (size_t)n * C * HW + p;
    u16* d = dst + (size_t)idx * C;
    for (int c8 = 0; c8 < C; c8 += 8) {
        s8v v;
#pragma unroll
        for (int i = 0; i < 8; ++i)
            v[i] = (short)f2b(s[(size_t)(c8 + i) * HW]);
        *(s8v*)(d + c8) = v;
    }
}

// ===========================================================================
// backward_warp from dense NHWC bf16 frame -> halo'd NHWC dst slot (192/96)
// ===========================================================================
__global__ __launch_bounds__(256) void warp_nhwc(
    const u16* __restrict__ fr, const float* __restrict__ flow,
    u16* __restrict__ dst, int chb, int C, int H, int W, int CALLOC, int total)
{
    int HW = H * W;
    int idx = blockIdx.x * 256 + threadIdx.x;
    if (idx >= total) return;
    int n = idx / HW, r = idx - n * HW;
    int i = r / W, j = r - i * W;

    float fx = flow[((size_t)n * 2 + 0) * HW + r];
    float fy = flow[((size_t)n * 2 + 1) * HW + r];
    float x = (float)j + fx * ((float)W / (float)(W - 1));
    float y = (float)i + fy * ((float)H / (float)(H - 1));
    x = fminf(fmaxf(x, 0.f), (float)(W - 1));
    y = fminf(fmaxf(y, 0.f), (float)(H - 1));
    float x0f = floorf(x), y0f = floorf(y);
    int ix0 = (int)x0f, iy0 = (int)y0f;
    int ix1 = ix0 + 1; if (ix1 > W - 1) ix1 = W - 1;
    int iy1 = iy0 + 1; if (iy1 > H - 1) iy1 = H - 1;
    float wx = x - x0f, wy = y - y0f;
    float w00 = (1.f - wx) * (1.f - wy), w01 = wx * (1.f - wy);
    float w10 = (1.f - wx) * wy,         w11 = wx * wy;

    const u16* fb  = fr + (size_t)n * HW * C;
    const u16* p00 = fb + (size_t)(iy0 * W + ix0) * C;
    const u16* p01 = fb + (size_t)(iy0 * W + ix1) * C;
    const u16* p10 = fb + (size_t)(iy1 * W + ix0) * C;
    const u16* p11 = fb + (size_t)(iy1 * W + ix1) * C;
    u16* db = dst + ((size_t)n * (H + 2) * (W + 2) + (size_t)(i + 1) * (W + 2) + (j + 1)) * CALLOC + chb;

    for (int c8 = 0; c8 < C; c8 += 8) {
        s8v a = *(const s8v*)(p00 + c8);
        s8v b = *(const s8v*)(p01 + c8);
        s8v c = *(const s8v*)(p10 + c8);
        s8v d = *(const s8v*)(p11 + c8);
        s8v o;
#pragma unroll
        for (int t = 0; t < 8; ++t)
            o[t] = (short)f2b(w00 * b2f((u16)a[t]) + w01 * b2f((u16)b[t])
                            + w10 * b2f((u16)c[t]) + w11 * b2f((u16)d[t]));
        *(s8v*)(db + c8) = o;
    }
}

// ===========================================================================
// MFMA implicit-GEMM 3x3 conv — round-15/17/19 verified structure (GLD16
// input staging + double-buffered weight LDS; integer-parity bilinear
// SRC_MODE=1).
//  SRC_MODE 0: halo'd NHWC
//  SRC_MODE 1: fused 2x-bilinear-upsample of virtual concat [A | B]
//  OUT_MODE 0: halo'd NHWC, 1: dense NHWC, 2: NCHW fp32
// HT=8/4: LDS-per-block halving -> +blocks/CU (R14 verified mechanism).
// ===========================================================================
template<int CINP, int CHUNK, int CIN_ALLOC, int COUTP, int COUT, int STORE_LIM,
         int HO, int WO, int HT, int STRIDE, int RELU, int SRC_MODE, int OUT_MODE, int OCALLOC>
__global__ __launch_bounds__(256) void conv_k(
    const u16* __restrict__ srcA, const u16* __restrict__ srcB,
    long nsA, int rsA, int cA, long nsB, int rsB, int cB, int splitC,
    const u16* __restrict__ wt, const float* __restrict__ bias,
    void* __restrict__ outv)
{
    constexpr int WROWS = (HT >= 4) ? HT / 4 : 1;
    constexpr int ROWS  = (STRIDE == 1) ? HT + 2 : 2 * HT + 1;
    constexpr int COLS  = (STRIDE == 1) ? 18 : 33;
    constexpr int SUBS  = CHUNK / 8;
    constexpr int LSUB  = (SUBS == 8) ? 3 : 2;
    constexpr int XM    = SUBS - 1;
    constexpr int CH2   = CHUNK * 2;
    constexpr int NCHK  = CINP / CHUNK;
    constexpr int KK    = CHUNK / 32;
    constexpr int MT    = COUTP / 16;
    constexpr int NPX   = ROWS * COLS;
    constexpr int IN_B  = NPX * CH2;
    constexpr int W_B   = COUTP * CH2;
    constexpr int WI    = WO * STRIDE;
    constexpr int Hs    = HO / 2, Ws = WO / 2;
    constexpr long NSO  = (OUT_MODE == 0) ? (long)(HO + 2) * (WO + 2) * OCALLOC
                                          : (long)HO * WO * OCALLOC;

    __shared__ s8v ldsv[(IN_B + 2 * W_B) / 16];
    char* lds  = (char*)ldsv;
    char* ldw0 = lds + IN_B;
    char* ldw1 = ldw0 + W_B;

    const int tid  = threadIdx.x;
    const int wv   = tid >> 6;
    const int lane = tid & 63;
    const int lr   = lane & 15;
    const int koct = lane >> 4;
    const int bx   = blockIdx.x, n = blockIdx.z;
    const int tx   = (bx % (WO / 16)) * 16;
    const int ty   = (bx / (WO / 16)) * HT;

    f4v acc[MT][WROWS];
#pragma unroll
    for (int m = 0; m < MT; ++m)
#pragma unroll
        for (int r = 0; r < WROWS; ++r) acc[m][r] = (f4v){0.f, 0.f, 0.f, 0.f};

    float bv[MT][4];
#pragma unroll
    for (int m = 0; m < MT; ++m)
#pragma unroll
        for (int j = 0; j < 4; ++j) {
            int co = m * 16 + koct * 4 + j;
            bv[m][j] = (co < COUT) ? bias[co] : 0.f;
        }

    for (int cig = 0; cig < NCHK; ++cig) {
        if (cig) __syncthreads();

        // ---------------- stage input chunk ----------------
        if constexpr (SRC_MODE == 0) {
            const u16* ns = srcA + (size_t)n * nsA;
            if (CIN_ALLOC >= CINP || (cig + 1) * CHUNK <= CIN_ALLOC) {
                for (int t = tid; t < NPX * SUBS; t += 256) {
                    int q = t >> LSUB, sub = t & XM;
                    int iy = q / COLS, ix = q - iy * COLS;
                    int xr = (STRIDE == 1) ? (q & XM) : ((q >> 1) & XM);
                    int ci0 = cig * CHUNK + (sub ^ xr) * 8;
                    const u16* g = ns + ((size_t)(ty * STRIDE + iy) * (WI + 2)
                                         + (tx * STRIDE + ix)) * CIN_ALLOC + ci0;
                    GLD16(g, lds + t * 16);
                }
            } else {
                for (int t = tid; t < NPX * SUBS; t += 256) {
                    int q = t >> LSUB, sub = t & XM;
                    int iy = q / COLS, ix = q - iy * COLS;
                    int xr = (STRIDE == 1) ? (q & XM) : ((q >> 1) & XM);
                    int ci0 = cig * CHUNK + (sub ^ xr) * 8;
                    s8v v = {0,0,0,0,0,0,0,0};
                    if (ci0 < CIN_ALLOC)
                        v = *(const s8v*)(ns + ((size_t)(ty * STRIDE + iy) * (WI + 2)
                                                + (tx * STRIDE + ix)) * CIN_ALLOC + ci0);
                    *(s8v*)(lds + t * 16) = v;
                }
            }
        } else {   // SRC_MODE == 1: fused up2x of [A | B], integer bilinear
            for (int t = tid; t < NPX * SUBS; t += 256) {
                int q = t >> LSUB, sub = t & XM;
                int iy = q / COLS, ix = q - iy * COLS;
                int ssub = sub ^ (q & XM);
                int ci0 = cig * CHUNK + ssub * 8;
                int gy = ty + iy - 1, gx = tx + ix - 1;
                s8v val = {0,0,0,0,0,0,0,0};
                if ((unsigned)gy < (unsigned)HO && (unsigned)gx < (unsigned)WO) {
                    const u16* sp; int rs, cal, cof; long nss;
                    if (ci0 < splitC) { sp = srcA; nss = nsA; rs = rsA; cal = cA; cof = ci0; }
                    else              { sp = srcB; nss = nsB; rs = rsB; cal = cB; cof = ci0 - splitC; }
                    sp += (size_t)n * nss;
                    int y0 = (gy >> 1) + (gy & 1) - 1;
                    int x0 = (gx >> 1) + (gx & 1) - 1;
                    float wy = (gy & 1) ? 0.25f : 0.75f;
                    float wx = (gx & 1) ? 0.25f : 0.75f;
                    int y1 = min(y0 + 1, Hs - 1); y0 = max(y0, 0);
                    int x1 = min(x0 + 1, Ws - 1); x0 = max(x0, 0);
                    const s8v a = *(const s8v*)(sp + (size_t)y0 * rs + (size_t)x0 * cal + cof);
                    const s8v b = *(const s8v*)(sp + (size_t)y0 * rs + (size_t)x1 * cal + cof);
                    const s8v c = *(const s8v*)(sp + (size_t)y1 * rs + (size_t)x0 * cal + cof);
                    const s8v d = *(const s8v*)(sp + (size_t)y1 * rs + (size_t)x1 * cal + cof);
                    float w00 = (1.f - wx) * (1.f - wy), w01 = wx * (1.f - wy);
                    float w10 = (1.f - wx) * wy,         w11 = wx * wy;
#pragma unroll
                    for (int i = 0; i < 8; ++i) {
                        float v = w00 * b2f((u16)a[i]) + w01 * b2f((u16)b[i])
                                + w10 * b2f((u16)c[i]) + w11 * b2f((u16)d[i]);
                        val[i] = (short)f2b(v);
                    }
                }
                *(s8v*)(lds + t * 16) = val;
            }
        }

        // ---------------- weight slice staging (double-buffered LDS) ------
        auto stageW = [&](int s, char* dstb) {
            for (int t = tid; t < COUTP * SUBS; t += 256) {
                int co = t >> LSUB, sub = t & XM;
                int ssub = sub ^ (co & XM);
                const u16* g = wt + ((size_t)(s * COUTP + co) * CINP + cig * CHUNK + ssub * 8);
                GLD16(g, dstb + t * 16);
            }
        };
        stageW(0, ldw0);

#pragma unroll
        for (int s = 0; s < 9; ++s) {
            __syncthreads();
            if (s < 8) stageW(s + 1, (s & 1) ? ldw0 : ldw1);
            char* wc = (s & 1) ? ldw1 : ldw0;
            const int dy = s / 3, dx = s - dy * 3;
#pragma unroll
            for (int kk = 0; kk < KK; ++kk) {
                const int koff = kk * 64 + koct * 16;
                s8v bfr[WROWS];
#pragma unroll
                for (int r = 0; r < WROWS; ++r) {
                    int orow = wv * WROWS + r;
                    int q, xr;
                    if (STRIDE == 1) { q = (orow + dy) * COLS + lr + dx; xr = q & XM; }
                    else             { q = (2 * orow + dy) * COLS + 2 * lr + dx; xr = (q >> 1) & XM; }
                    bfr[r] = *(const s8v*)(lds + q * CH2 + (koff ^ (xr << 4)));
                }
#pragma unroll
                for (int m = 0; m < MT; ++m) {
                    s8v afr = *(const s8v*)(wc + (m * 16 + lr) * CH2 + (koff ^ ((lr & XM) << 4)));
#pragma unroll
                    for (int r = 0; r < WROWS; ++r)
                        acc[m][r] = __builtin_amdgcn_mfma_f32_16x16x32_bf16(afr, bfr[r], acc[m][r], 0, 0, 0);
                }
            }
        }
    }

    // ---------------- epilogue ----------------
#pragma unroll
    for (int m = 0; m < MT; ++m) {
#pragma unroll
        for (int r = 0; r < WROWS; ++r) {
            int row = ty + wv * WROWS + r, col = tx + lr;
            float x0 = acc[m][r][0] + bv[m][0];
            float x1 = acc[m][r][1] + bv[m][1];
            float x2 = acc[m][r][2] + bv[m][2];
            float x3 = acc[m][r][3] + bv[m][3];
            if (RELU) {
                x0 = fmaxf(x0, 0.f); x1 = fmaxf(x1, 0.f);
                x2 = fmaxf(x2, 0.f); x3 = fmaxf(x3, 0.f);
            }
            int co0 = m * 16 + koct * 4;
            if constexpr (OUT_MODE == 2) {
                float* op = (float*)outv;
                float xs[4] = {x0, x1, x2, x3};
#pragma unroll
                for (int j = 0; j < 4; ++j)
                    if (co0 + j < STORE_LIM)
                        op[((size_t)(n * 4 + co0 + j) * HO + row) * WO + col] = xs[j];
            } else {
                size_t pix = (OUT_MODE == 0)
                    ? ((size_t)(row + 1) * (WO + 2) + (col + 1))
                    : ((size_t)row * WO + col);
                u16* ob = (u16*)outv + (size_t)n * NSO + pix * OCALLOC + co0;
                if (co0 + 3 < STORE_LIM) {
                    unsigned lo = (unsigned)f2b(x0) | ((unsigned)f2b(x1) << 16);
                    unsigned hi = (unsigned)f2b(x2) | ((unsigned)f2b(x3) << 16);
                    *(u2v*)ob = (u2v){lo, hi};
                } else {
                    float xs[4] = {x0, x1, x2, x3};
#pragma unroll
                    for (int j = 0; j < 4; ++j)
                        if (co0 + j < STORE_LIM) ob[j] = f2b(xs[j]);
                }
            }
        }
    }
}

// ===========================================================================
extern "C" void kernel_launch(void* const* d_in, const int* in_sizes, int n_in,
                              void* d_out, int out_size, void* d_ws, size_t ws_size,
                              hipStream_t stream)
{
    const float* img0  = (const float*)d_in[0];
    const float* img1  = (const float*)d_in[1];
    const float* ft0   = (const float*)d_in[2];
    const float* ft1   = (const float*)d_in[3];
    const float* ft0s2 = (const float*)d_in[4];
    const float* ft1s2 = (const float*)d_in[5];
    const float* ft0s4 = (const float*)d_in[6];
    const float* ft1s4 = (const float*)d_in[7];
    const float* c0_0  = (const float*)d_in[8];
    const float* c0_1  = (const float*)d_in[9];
    const float* c0_2  = (const float*)d_in[10];
    const float* c1_0  = (const float*)d_in[11];
    const float* c1_1  = (const float*)d_in[12];
    const float* c1_2  = (const float*)d_in[13];
    const float* wd0a = (const float*)d_in[14]; const float* bd0a = (const float*)d_in[15];
    const float* wd0b = (const float*)d_in[16]; const float* bd0b = (const float*)d_in[17];
    const float* wd1a = (const float*)d_in[18]; const float* bd1a = (const float*)d_in[19];
    const float* wd1b = (const float*)d_in[20]; const float* bd1b = (const float*)d_in[21];
    const float* wd2a = (const float*)d_in[22]; const float* bd2a = (const float*)d_in[23];
    const float* wd2b = (const float*)d_in[24]; const float* bd2b = (const float*)d_in[25];
    const float* wu0  = (const float*)d_in[26]; const float* bu0  = (const float*)d_in[27];
    const float* wu1  = (const float*)d_in[28]; const float* bu1  = (const float*)d_in[29];
    const float* wu2  = (const float*)d_in[30]; const float* bu2  = (const float*)d_in[31];
    const float* wfin = (const float*)d_in[32]; const float* bfin = (const float*)d_in[33];

    u16* ws = (u16*)d_ws;
    // region plan (bf16 elems, total 86,314,880 = 172.6 MB — proven)
    u16* s0in = ws + 0;          // 4 x 386x386 x 72 (dead after d0a)
    u16* x2   = ws + 0;          // halo'd, same geometry (u2 output; halo stays 0)
    u16* s1in = ws + 42913152;   // 4 x 194x194 x 128
    u16* scrB = ws + 42913152;   // 384-level scratch [2HW][64] (dead before d0b)
    u16* s2in = ws + 62182784;   // 4 x 98x98 x 192
    u16* scr  = ws + 69558656;   // 192/96-level warp scratch (aliases t0/t1)
    u16* t0   = ws + 69558656;   // 4 x 194x194 x 32
    u16* t1   = ws + 74376064;   // 4 x 98x98 x 64
    u16* t2   = ws + 76834688;   // 4 x 50x50 x 96
    u16* s2b  = ws + 77794688;   // 4 x 48x48 x 96 (dense)
    u16* x0   = ws + 78679424;   // 4 x 96x96 x 64 (dense)
    u16* x1   = ws + 81038720;   // 4 x 192x192 x 32 (dense)
    u16* wtb  = ws + 85757312;
    u16* Wd0a = wtb;
    u16* Wd0b = Wd0a + 27648;
    u16* Wd1a = Wd0b + 9216;
    u16* Wd1b = Wd1a + 73728;
    u16* Wd2a = Wd1b + 36864;
    u16* Wd2b = Wd2a + 165888;
    u16* Wu0  = Wd2b + 82944;
    u16* Wu1  = Wu0 + 55296;
    u16* Wu2  = Wu1 + 36864;
    u16* Wfin = Wu2 + 46080;

    const int HW384 = 147456, HW192 = 36864, HW96 = 9216;

    // ---- 1) warp stage FIRST. 384-level: batch pairs, both frames staged
    //         interleaved in scrB, fused img+warp0+warp1 -> full 144B lines.
    for (int g = 0; g < 2; ++g) {
        int n0 = 2 * g;
        t_nhwc64<<<DIV_UP(2 * HW384, 256), 256, 0, stream>>>(
            c0_0 + (size_t)n0 * 32 * HW384, scrB, HW384, 2 * HW384, 0);
        t_nhwc64<<<DIV_UP(2 * HW384, 256), 256, 0, stream>>>(
            c1_0 + (size_t)n0 * 32 * HW384, scrB, HW384, 2 * HW384, 32);
        warp_full<<<DIV_UP(2 * HW384, 256), 256, 0, stream>>>(
            scrB,
            img0 + (size_t)n0 * 3 * HW384, img1 + (size_t)n0 * 3 * HW384,
            ft0 + (size_t)n0 * 2 * HW384, ft1 + (size_t)n0 * 2 * HW384,
            s0in + (size_t)n0 * 386 * 386 * 72, 2 * HW384);
    }
    for (int f = 0; f < 2; ++f) {
        t_nhwc<<<DIV_UP(4 * HW192, 256), 256, 0, stream>>>(
            f ? c1_1 : c0_1, scr, 48, HW192, 4 * HW192);
        warp_nhwc<<<DIV_UP(4 * HW192, 256), 256, 0, stream>>>(
            scr, f ? ft1s2 : ft0s2, s1in, f ? 80 : 32, 48, 192, 192, 128, 4 * HW192);
    }
    for (int f = 0; f < 2; ++f) {
        t_nhwc<<<DIV_UP(4 * HW96, 256), 256, 0, stream>>>(
            f ? c1_2 : c0_2, scr, 64, HW96, 4 * HW96);
        warp_nhwc<<<DIV_UP(4 * HW96, 256), 256, 0, stream>>>(
            scr, f ? ft1s4 : ft0s4, s2in, f ? 128 : 64, 64, 96, 96, 192, 4 * HW96);
    }

    // ---- 2) halo rings
    HZ6 hz = {{ {s0in, 384, 384, 72}, {s1in, 192, 192, 128}, {s2in, 96, 96, 192},
                {t0, 192, 192, 32},   {t1, 96, 96, 64},      {t2, 48, 48, 96} }};
    halo_zero<<<dim3(DIV_UP(4 * 386 * 386, 256), 6), 256, 0, stream>>>(hz);

    // ---- 3) weight transposes
    WT10 wt = {{ {wd0a, Wd0a, 32, 70, 32, 96, 1},  {wd0b, Wd0b, 32, 32, 32, 32, 0},
                 {wd1a, Wd1a, 64, 128, 64, 128, 0},{wd1b, Wd1b, 64, 64, 64, 64, 0},
                 {wd2a, Wd2a, 96, 192, 96, 192, 0},{wd2b, Wd2b, 96, 96, 96, 96, 0},
                 {wu0,  Wu0,  64, 96, 64, 96, 0},  {wu1,  Wu1,  32, 128, 32, 128, 0},
                 {wu2,  Wu2,  70, 64, 80, 64, 0},  {wfin, Wfin, 4, 70, 16, 96, 0} }};
    wtrans<<<dim3(DIV_UP(9 * 96 * 192, 256), 10), 256, 0, stream>>>(wt);

    // ---- down0
    conv_k<96,32,72, 32,32,32, 192,192,4,2,1, 0,0,32>
        <<<dim3(12*48,1,4),256,0,stream>>>(s0in,nullptr, 386L*386*72,0,0, 0,0,0,0, Wd0a,bd0a,t0);
    conv_k<32,32,32, 32,32,32, 192,192,8,1,1, 0,0,128>
        <<<dim3(12*24,1,4),256,0,stream>>>(t0,nullptr, 194L*194*32,0,0, 0,0,0,0, Wd0b,bd0b,s1in);

    // ---- down1
    conv_k<128,32,128, 64,64,64, 96,96,4,2,1, 0,0,64>
        <<<dim3(6*24,1,4),256,0,stream>>>(s1in,nullptr, 194L*194*128,0,0, 0,0,0,0, Wd1a,bd1a,t1);
    conv_k<64,64,64, 64,64,64, 96,96,4,1,1, 0,0,192>
        <<<dim3(6*24,1,4),256,0,stream>>>(t1,nullptr, 98L*98*64,0,0, 0,0,0,0, Wd1b,bd1b,s2in);

    // ---- down2
    conv_k<192,32,192, 96,96,96, 48,48,4,2,1, 0,0,96>
        <<<dim3(3*12,1,4),256,0,stream>>>(s2in,nullptr, 98L*98*192,0,0, 0,0,0,0, Wd2a,bd2a,t2);
    conv_k<96,32,96, 96,96,96, 48,48,4,1,1, 0,1,96>
        <<<dim3(3*12,1,4),256,0,stream>>>(t2,nullptr, 50L*50*96,0,0, 0,0,0,0, Wd2b,bd2b,s2b);

    // ---- decoder (fused up2x staging)
    conv_k<96,32,96, 64,64,64, 96,96,4,1,1, 1,1,64>
        <<<dim3(6*24,1,4),256,0,stream>>>(s2b,s2b, 48L*48*96,48*96,96, 48L*48*96,48*96,96, 96,
                                          Wu0,bu0,x0);
    conv_k<128,64,128, 32,32,32, 192,192,8,1,1, 1,1,32>
        <<<dim3(12*24,1,4),256,0,stream>>>(x0, s2in + (size_t)(98+1)*192,
                                           96L*96*64,96*64,64, 98L*98*192,98*192,192, 64,
                                           Wu1,bu1,x1);
    // u2: HT=4 (LDS 43.5KB -> 34.3KB, 3 -> 4 blocks/CU; R14 mechanism)
    conv_k<64,64,64, 80,70,70, 384,384,4,1,1, 1,0,72>
        <<<dim3(24*96,1,4),256,0,stream>>>(x1, s1in + (size_t)(194+1)*128,
                                           192L*192*32,192*32,32, 194L*194*128,194*128,128, 32,
                                           Wu2,bu2,x2);

    // ---- final conv (halo'd x2, GLD16 fast path + reg tail), HT=8, fp32 out
    conv_k<96,32,72, 16,4,4, 384,384,8,1,0, 0,2,0>
        <<<dim3(24*48,1,4),256,0,stream>>>(x2,nullptr, 386L*386*72,0,0, 0,0,0,0, Wfin,bfin,d_out);
}